// Round 4
// baseline (400.140 us; speedup 1.0000x reference)
//
#include <hip/hip_runtime.h>
#include <math.h>

// B=16, C=3, H=W=512, P=16, D=128, NH=4, hd=32, GH=GW=32, NP=1024, PD=768, NV=256, FF=512
typedef unsigned short ushort_t;
typedef __attribute__((ext_vector_type(8))) short bf16x8;
typedef __attribute__((ext_vector_type(4))) float f32x4;
typedef __attribute__((ext_vector_type(16))) float f32x16;
typedef __attribute__((ext_vector_type(2))) unsigned uint2v;

__device__ __forceinline__ ushort_t f2bf(float f){
  union{float f; unsigned u;} v; v.f = f;
  unsigned r = v.u + 0x7FFFu + ((v.u >> 16) & 1u);
  return (ushort_t)(r >> 16);
}
__device__ __forceinline__ float bf2f(ushort_t h){
  union{unsigned u; float f;} v; v.u = ((unsigned)h) << 16; return v.f;
}
__device__ __forceinline__ float gelu_exact(float v){
  return 0.5f * v * (1.f + erff(v * 0.70710678118654752f));
}
#define GLD16(gp, lp) __builtin_amdgcn_global_load_lds( \
    (const __attribute__((address_space(1))) void*)(gp), \
    (__attribute__((address_space(3))) void*)(lp), 16, 0, 0)

static __device__ __forceinline__ f32x4 mfma16(bf16x8 a, bf16x8 b, f32x4 c){
  return __builtin_amdgcn_mfma_f32_16x16x32_bf16(a, b, c, 0, 0, 0);
}
static __device__ __forceinline__ f32x16 mfma32(bf16x8 a, bf16x8 b, f32x16 c){
  return __builtin_amdgcn_mfma_f32_32x32x16_bf16(a, b, c, 0, 0, 0);
}

// ---------------------------------------------------------------------------
// bf16 MFMA GEMM: C[M,N] = A[M,K] @ W[N,K]^T + bias.
// BT x BT tile, 4 waves (2x2), BK=64, XOR-swizzled LDS via global_load_lds.
// SRC: 0 = plain A, 1 = patchify gather from bf16 image.
// EPI: 0 = bf16 out, 2 = fp32 unpatchify scatter,
//      3 = qkv mode: cols<128 scaled by qs; cols>=256 stored transposed to vT.
// ---------------------------------------------------------------------------
template<int BT, int MI, int SRC, int EPI>
__global__ __launch_bounds__(256) void mfma_gemm(
    const ushort_t* __restrict__ A, const ushort_t* __restrict__ W,
    const float* __restrict__ bias, void* __restrict__ Cout,
    int M, int N, int K, ushort_t* __restrict__ vT, int slog, float qs)
{
  __shared__ ushort_t smem[BT*64 + BT*64];
  ushort_t* Al = smem;
  ushort_t* Wl = smem + BT*64;
  const int tid = threadIdx.x;
  const int lane = tid & 63, w = tid >> 6;
  const int wr = w >> 1, wc = w & 1;
  const int g = lane >> 4, lq = lane & 15;
  const int m0 = blockIdx.y * BT, n0 = blockIdx.x * BT;

  const f32x4 zf = {0.f, 0.f, 0.f, 0.f};
  f32x4 acc[MI][MI];
#pragma unroll
  for (int i = 0; i < MI; ++i)
#pragma unroll
    for (int j = 0; j < MI; ++j) acc[i][j] = zf;

  float bv[MI];
#pragma unroll
  for (int ni = 0; ni < MI; ++ni) bv[ni] = bias[n0 + wc*(BT/2) + ni*16 + lq];

  const int KT = K >> 6;
  for (int kt = 0; kt < KT; ++kt) {
    if (kt) __syncthreads();
    const int k0 = kt << 6;
#pragma unroll
    for (int i = 0; i < BT/32; ++i) {
      int chunk = i*256 + tid;
      int row = chunk >> 3, c = chunk & 7;
      int kk = k0 + ((c ^ (row & 7)) << 3);
      const ushort_t* src;
      if (SRC == 0) {
        src = A + (size_t)(m0 + row) * K + kk;
      } else {
        int gm = m0 + row;
        int bb = gm >> 10, pp = gm & 1023, gh = pp >> 5, gw = pp & 31;
        int ci = kk >> 8, rem = kk & 255, py = rem >> 4, px = rem & 15;
        src = A + ((size_t)((bb*3 + ci)*512 + gh*16 + py) * 512 + gw*16 + px);
      }
      GLD16(src, (char*)Al + chunk*16);
    }
#pragma unroll
    for (int i = 0; i < BT/32; ++i) {
      int chunk = i*256 + tid;
      int row = chunk >> 3, c = chunk & 7;
      int kk = k0 + ((c ^ (row & 7)) << 3);
      GLD16(W + (size_t)(n0 + row) * K + kk, (char*)Wl + chunk*16);
    }
    __syncthreads();
#pragma unroll
    for (int ks = 0; ks < 2; ++ks) {
      bf16x8 af[MI], bfr[MI];
#pragma unroll
      for (int mi = 0; mi < MI; ++mi) {
        int row = wr*(BT/2) + mi*16 + lq;
        int c = (ks*4 + g) ^ (row & 7);
        af[mi] = *(const bf16x8*)((const char*)Al + row*128 + c*16);
      }
#pragma unroll
      for (int ni = 0; ni < MI; ++ni) {
        int row = wc*(BT/2) + ni*16 + lq;
        int c = (ks*4 + g) ^ (row & 7);
        bfr[ni] = *(const bf16x8*)((const char*)Wl + row*128 + c*16);
      }
#pragma unroll
      for (int mi = 0; mi < MI; ++mi)
#pragma unroll
        for (int ni = 0; ni < MI; ++ni)
          acc[mi][ni] = mfma16(af[mi], bfr[ni], acc[mi][ni]);
    }
  }

  if (EPI == 3 && n0 >= 256) {
    const int Sm1 = (1 << slog) - 1;
#pragma unroll
    for (int mi = 0; mi < MI; ++mi) {
      int gm0 = m0 + wr*(BT/2) + mi*16 + g*4;
      int bb = gm0 >> slog, s0 = gm0 & Sm1;
#pragma unroll
      for (int ni = 0; ni < MI; ++ni) {
        int n = n0 + wc*(BT/2) + ni*16 + lq;
        int vcol = n - 256, hh = vcol >> 5, dd = vcol & 31;
        unsigned pw0 = ((unsigned)f2bf(acc[mi][ni][0] + bv[ni])) |
                       (((unsigned)f2bf(acc[mi][ni][1] + bv[ni])) << 16);
        unsigned pw1 = ((unsigned)f2bf(acc[mi][ni][2] + bv[ni])) |
                       (((unsigned)f2bf(acc[mi][ni][3] + bv[ni])) << 16);
        uint2 pk; pk.x = pw0; pk.y = pw1;
        *(uint2*)(vT + (((size_t)(bb*4 + hh)*32 + dd) << slog) + s0) = pk;
      }
    }
    return;
  }

  if (EPI == 2) {
    float* img = (float*)Cout;
#pragma unroll
    for (int mi = 0; mi < MI; ++mi) {
#pragma unroll
      for (int r = 0; r < 4; ++r) {
        int gm = m0 + wr*(BT/2) + mi*16 + g*4 + r;
        int bb = gm >> 10, pp = gm & 1023, gh = pp >> 5, gw = pp & 31;
#pragma unroll
        for (int ni = 0; ni < MI; ++ni) {
          int n = n0 + wc*(BT/2) + ni*16 + lq;
          int ci = n >> 8, rem = n & 255, py = rem >> 4, px = rem & 15;
          img[(size_t)((bb*3 + ci)*512 + gh*16 + py)*512 + gw*16 + px] =
              acc[mi][ni][r] + bv[ni];
        }
      }
    }
  } else {
    const float cs = (EPI == 3 && n0 < 128) ? qs : 1.0f;
    __syncthreads();
    constexpr int CPR = BT/8;
#pragma unroll
    for (int mi = 0; mi < MI; ++mi)
#pragma unroll
      for (int ni = 0; ni < MI; ++ni)
#pragma unroll
        for (int r = 0; r < 4; ++r) {
          int row = wr*(BT/2) + mi*16 + g*4 + r;
          int col = wc*(BT/2) + ni*16 + lq;
          float v = acc[mi][ni][r] + bv[ni];
          if (EPI == 3) v *= cs;
          int cc = (col >> 3) ^ (row & (CPR-1));
          smem[row*BT + cc*8 + (col & 7)] = f2bf(v);
        }
    __syncthreads();
    ushort_t* Co = (ushort_t*)Cout;
#pragma unroll
    for (int i = 0; i < BT*BT/2048; ++i) {
      int chunk = i*256 + tid;
      int row = chunk / CPR, cc = chunk % CPR;
      int c = cc ^ (row & (CPR-1));
      bf16x8 v = *(const bf16x8*)((const char*)smem + chunk*16);
      *(bf16x8*)(Co + (size_t)(m0+row)*N + n0 + c*8) = v;
    }
  }
}

// ---------------------------------------------------------------------------
// GEMM + fused bias + residual + LayerNorm:
//   X = LN(X + A@W^T + bias) * lnw + lnb     (N = 128, in-place on X)
// BM=32 rows/block, 4 waves N-split (wave w -> cols w*32..w*32+31).
// ---------------------------------------------------------------------------
template<int KK>
__global__ __launch_bounds__(256) void gemm_ln(
    const ushort_t* __restrict__ A, const ushort_t* __restrict__ W,
    const float* __restrict__ bias, ushort_t* __restrict__ X,
    const float* __restrict__ lnw, const float* __restrict__ lnb)
{
  __shared__ __align__(16) ushort_t Al[32*64];
  __shared__ __align__(16) ushort_t Wl[128*64];
  __shared__ float red[2][32][4];
  const int tid = threadIdx.x, lane = tid & 63, w = tid >> 6;
  const int g = lane >> 4, lq = lane & 15;
  const int m0 = blockIdx.x * 32;
  const f32x4 zf = {0.f,0.f,0.f,0.f};
  f32x4 acc[2][2] = {{zf,zf},{zf,zf}};

#pragma unroll
  for (int kt = 0; kt < KK/64; ++kt) {
    if (kt) __syncthreads();
    const int k0 = kt*64;
    { int row = tid >> 3, c = tid & 7;
      int kk = k0 + ((c ^ (row & 7)) << 3);
      GLD16(A + (size_t)(m0+row)*KK + kk, (char*)Al + tid*16); }
#pragma unroll
    for (int i = 0; i < 4; ++i) {
      int chunk = i*256 + tid, row = chunk >> 3, c = chunk & 7;
      int kk = k0 + ((c ^ (row & 7)) << 3);
      GLD16(W + (size_t)row*KK + kk, (char*)Wl + chunk*16);
    }
    __syncthreads();
#pragma unroll
    for (int ks = 0; ks < 2; ++ks) {
      bf16x8 af[2], bfr[2];
#pragma unroll
      for (int mi = 0; mi < 2; ++mi) {
        int row = mi*16 + lq, c = (ks*4 + g) ^ (row & 7);
        af[mi] = *(const bf16x8*)((const char*)Al + row*128 + c*16);
      }
#pragma unroll
      for (int ni = 0; ni < 2; ++ni) {
        int row = w*32 + ni*16 + lq, c = (ks*4 + g) ^ (row & 7);
        bfr[ni] = *(const bf16x8*)((const char*)Wl + row*128 + c*16);
      }
#pragma unroll
      for (int mi = 0; mi < 2; ++mi)
#pragma unroll
        for (int ni = 0; ni < 2; ++ni)
          acc[mi][ni] = mfma16(af[mi], bfr[ni], acc[mi][ni]);
    }
  }

  // epilogue: bias + residual, row mean/var, normalize, store
  float bv[2], lwv[2], lbv[2];
#pragma unroll
  for (int ni = 0; ni < 2; ++ni) {
    int col = w*32 + ni*16 + lq;
    bv[ni] = bias[col]; lwv[ni] = lnw[col]; lbv[ni] = lnb[col];
  }
  float v[2][2][4];
#pragma unroll
  for (int mi = 0; mi < 2; ++mi)
#pragma unroll
    for (int r = 0; r < 4; ++r) {
      int row = m0 + mi*16 + g*4 + r;
#pragma unroll
      for (int ni = 0; ni < 2; ++ni) {
        int col = w*32 + ni*16 + lq;
        v[mi][ni][r] = acc[mi][ni][r] + bv[ni] + bf2f(X[(size_t)row*128 + col]);
      }
      float s = v[mi][0][r] + v[mi][1][r];
      float q = v[mi][0][r]*v[mi][0][r] + v[mi][1][r]*v[mi][1][r];
      s += __shfl_xor(s,1); s += __shfl_xor(s,2); s += __shfl_xor(s,4); s += __shfl_xor(s,8);
      q += __shfl_xor(q,1); q += __shfl_xor(q,2); q += __shfl_xor(q,4); q += __shfl_xor(q,8);
      if (lq == 0) { red[0][mi*16+g*4+r][w] = s; red[1][mi*16+g*4+r][w] = q; }
    }
  __syncthreads();
#pragma unroll
  for (int mi = 0; mi < 2; ++mi)
#pragma unroll
    for (int r = 0; r < 4; ++r) {
      int rl = mi*16 + g*4 + r;
      float s = red[0][rl][0]+red[0][rl][1]+red[0][rl][2]+red[0][rl][3];
      float q = red[1][rl][0]+red[1][rl][1]+red[1][rl][2]+red[1][rl][3];
      float mean = s * 0.0078125f;
      float var = q * 0.0078125f - mean*mean;
      float rstd = rsqrtf(var + 1e-5f);
#pragma unroll
      for (int ni = 0; ni < 2; ++ni) {
        int col = w*32 + ni*16 + lq;
        X[(size_t)(m0+rl)*128 + col] = f2bf((v[mi][ni][r]-mean)*rstd*lwv[ni] + lbv[ni]);
      }
    }
}

// ---------------------------------------------------------------------------
// Fully fused FFN + residual + LayerNorm:
//   X = LN(X + gelu(X@W1^T + b1)@W2^T + b2) * lnw + lnb   (in-place on X)
// BM=32 rows/block. X staged once in LDS; H (32x512) lives in LDS between
// the two GEMMs. LDS = 8 + 32 + 16 + 1 KB = 57 KB -> 2 blocks/CU.
// ---------------------------------------------------------------------------
__global__ __launch_bounds__(256) void ffn_ln(
    ushort_t* __restrict__ X,
    const ushort_t* __restrict__ W1, const float* __restrict__ b1,
    const ushort_t* __restrict__ W2, const float* __restrict__ b2,
    const float* __restrict__ lnw, const float* __restrict__ lnb)
{
  __shared__ __align__(16) ushort_t Xl[2*32*64];   // 2 k-tiles, swizzled
  __shared__ __align__(16) ushort_t Hl[8*32*64];   // H as 8 k-tiles, swizzled
  __shared__ __align__(16) ushort_t Wl[128*64];    // W staging
  __shared__ float red[2][32][4];
  const int tid = threadIdx.x, lane = tid & 63, w = tid >> 6;
  const int g = lane >> 4, lq = lane & 15;
  const int m0 = blockIdx.x * 32;
  const f32x4 zf = {0.f,0.f,0.f,0.f};

  // stage X (32x128) once: A for GEMM1, all k-tiles
#pragma unroll
  for (int i = 0; i < 2; ++i) {
    int chunk = i*256 + tid;
    int kt = chunk >> 8, r8 = chunk & 255, row = r8 >> 3, c = r8 & 7;
    int kk = kt*64 + ((c ^ (row & 7)) << 3);
    GLD16(X + (size_t)(m0+row)*128 + kk, (char*)Xl + chunk*16);
  }

  // ---- GEMM1 + gelu -> Hl (hidden in 4 passes of 128) ----
#pragma unroll
  for (int hp = 0; hp < 4; ++hp) {
    f32x4 acc1[2][2] = {{zf,zf},{zf,zf}};
#pragma unroll
    for (int kt = 0; kt < 2; ++kt) {
      __syncthreads();
#pragma unroll
      for (int i = 0; i < 4; ++i) {
        int chunk = i*256 + tid, row = chunk >> 3, c = chunk & 7;
        int kk = kt*64 + ((c ^ (row & 7)) << 3);
        GLD16(W1 + (size_t)(hp*128 + row)*128 + kk, (char*)Wl + chunk*16);
      }
      __syncthreads();
#pragma unroll
      for (int ks = 0; ks < 2; ++ks) {
        bf16x8 af[2], bfr[2];
#pragma unroll
        for (int mi = 0; mi < 2; ++mi) {
          int row = mi*16 + lq, c = (ks*4 + g) ^ (row & 7);
          af[mi] = *(const bf16x8*)((const char*)Xl + kt*4096 + row*128 + c*16);
        }
#pragma unroll
        for (int ni = 0; ni < 2; ++ni) {
          int row = w*32 + ni*16 + lq, c = (ks*4 + g) ^ (row & 7);
          bfr[ni] = *(const bf16x8*)((const char*)Wl + row*128 + c*16);
        }
#pragma unroll
        for (int mi = 0; mi < 2; ++mi)
#pragma unroll
          for (int ni = 0; ni < 2; ++ni)
            acc1[mi][ni] = mfma16(af[mi], bfr[ni], acc1[mi][ni]);
      }
    }
    // gelu + write H to swizzled LDS
#pragma unroll
    for (int ni = 0; ni < 2; ++ni) {
      int hid = hp*128 + w*32 + ni*16 + lq;
      float bb = b1[hid];
      int hkt = hid >> 6, hc = (hid & 63) >> 3, he = hid & 7;
#pragma unroll
      for (int mi = 0; mi < 2; ++mi)
#pragma unroll
        for (int r = 0; r < 4; ++r) {
          int mrow = mi*16 + g*4 + r;
          float hv = gelu_exact(acc1[mi][ni][r] + bb);
          *(ushort_t*)((char*)Hl + hkt*4096 + mrow*128 +
                       ((hc ^ (mrow & 7)) << 4) + he*2) = f2bf(hv);
        }
    }
  }

  // ---- GEMM2 (K=512, A = Hl from LDS) ----
  f32x4 acc2[2][2] = {{zf,zf},{zf,zf}};
#pragma unroll
  for (int kt = 0; kt < 8; ++kt) {
    __syncthreads();
#pragma unroll
    for (int i = 0; i < 4; ++i) {
      int chunk = i*256 + tid, row = chunk >> 3, c = chunk & 7;
      int kk = kt*64 + ((c ^ (row & 7)) << 3);
      GLD16(W2 + (size_t)row*512 + kk, (char*)Wl + chunk*16);
    }
    __syncthreads();
#pragma unroll
    for (int ks = 0; ks < 2; ++ks) {
      bf16x8 af[2], bfr[2];
#pragma unroll
      for (int mi = 0; mi < 2; ++mi) {
        int row = mi*16 + lq, c = (ks*4 + g) ^ (row & 7);
        af[mi] = *(const bf16x8*)((const char*)Hl + kt*4096 + row*128 + c*16);
      }
#pragma unroll
      for (int ni = 0; ni < 2; ++ni) {
        int row = w*32 + ni*16 + lq, c = (ks*4 + g) ^ (row & 7);
        bfr[ni] = *(const bf16x8*)((const char*)Wl + row*128 + c*16);
      }
#pragma unroll
      for (int mi = 0; mi < 2; ++mi)
#pragma unroll
        for (int ni = 0; ni < 2; ++ni)
          acc2[mi][ni] = mfma16(af[mi], bfr[ni], acc2[mi][ni]);
    }
  }

  // epilogue: bias + residual + LN (same as gemm_ln)
  float bv[2], lwv[2], lbv[2];
#pragma unroll
  for (int ni = 0; ni < 2; ++ni) {
    int col = w*32 + ni*16 + lq;
    bv[ni] = b2[col]; lwv[ni] = lnw[col]; lbv[ni] = lnb[col];
  }
  float v[2][2][4];
#pragma unroll
  for (int mi = 0; mi < 2; ++mi)
#pragma unroll
    for (int r = 0; r < 4; ++r) {
      int row = m0 + mi*16 + g*4 + r;
#pragma unroll
      for (int ni = 0; ni < 2; ++ni) {
        int col = w*32 + ni*16 + lq;
        v[mi][ni][r] = acc2[mi][ni][r] + bv[ni] + bf2f(X[(size_t)row*128 + col]);
      }
      float s = v[mi][0][r] + v[mi][1][r];
      float q = v[mi][0][r]*v[mi][0][r] + v[mi][1][r]*v[mi][1][r];
      s += __shfl_xor(s,1); s += __shfl_xor(s,2); s += __shfl_xor(s,4); s += __shfl_xor(s,8);
      q += __shfl_xor(q,1); q += __shfl_xor(q,2); q += __shfl_xor(q,4); q += __shfl_xor(q,8);
      if (lq == 0) { red[0][mi*16+g*4+r][w] = s; red[1][mi*16+g*4+r][w] = q; }
    }
  __syncthreads();
#pragma unroll
  for (int mi = 0; mi < 2; ++mi)
#pragma unroll
    for (int r = 0; r < 4; ++r) {
      int rl = mi*16 + g*4 + r;
      float s = red[0][rl][0]+red[0][rl][1]+red[0][rl][2]+red[0][rl][3];
      float q = red[1][rl][0]+red[1][rl][1]+red[1][rl][2]+red[1][rl][3];
      float mean = s * 0.0078125f;
      float var = q * 0.0078125f - mean*mean;
      float rstd = rsqrtf(var + 1e-5f);
#pragma unroll
      for (int ni = 0; ni < 2; ++ni) {
        int col = w*32 + ni*16 + lq;
        X[(size_t)(m0+rl)*128 + col] = f2bf((v[mi][ni][r]-mean)*rstd*lwv[ni] + lbv[ni]);
      }
    }
}

// ---------------------------------------------------------------------------
// 32x32 MFMA flash attention, swapped QK^T, in-register softmax (no-max:
// shift-invariant, scores bounded for this model).
// qkv [B,S,384] bf16 (q pre-scaled by 1/sqrt(32)); vT [B,H,32,S] bf16.
// ---------------------------------------------------------------------------
template<int S, int JS>
__global__ __launch_bounds__(256) void attn32(
    const ushort_t* __restrict__ qkv, const ushort_t* __restrict__ vTg,
    ushort_t* __restrict__ o)
{
  constexpr int LDSB = (JS == 1) ? 16384 : 32768;
  __shared__ __align__(16) char smem[LDSB];
  const int tid = threadIdx.x, lane = tid & 63, w = tid >> 6;
  const int hi = lane >> 5, lq = lane & 31;
  int lin = blockIdx.x;
  int nid = (lin & 7) * 64 + (lin >> 3);
  int bx = nid & 7, bh = nid >> 3;
  int h = bh & 3, b = bh >> 2;
  const int q0 = (JS == 1) ? (bx*128 + w*32) : (bx*32);

  bf16x8 bq0 = *(const bf16x8*)(qkv + (size_t)(b*S + q0 + lq)*384 + h*32 + hi*8);
  bf16x8 bq1 = *(const bf16x8*)(qkv + (size_t)(b*S + q0 + lq)*384 + h*32 + 16 + hi*8);

  f32x16 O;
#pragma unroll
  for (int i = 0; i < 16; ++i) O[i] = 0.f;
  const f32x16 z16 = O;
  float l = 0.f;

  auto stageK = [&](char* Kb, int j0, int ci){
    int k = ci >> 2, cp = ci & 3, c = cp ^ (k & 3);
    GLD16(qkv + (size_t)(b*S + j0 + k)*384 + 128 + h*32 + c*8, Kb + ci*16);
  };
  auto stageV = [&](char* Vb, int j0, int ci){
    int d = ci >> 3, cp = ci & 7, c = cp ^ (d & 7);
    GLD16(vTg + (size_t)(bh*32 + d)*S + j0 + c*8, Vb + ci*16);
  };

  auto sm_pack = [&](const f32x16& stv, unsigned* wd){
    float p[16];
#pragma unroll
    for (int r = 0; r < 16; ++r) { p[r] = __expf(stv[r]); l += p[r]; }
#pragma unroll
    for (int i = 0; i < 8; ++i) {
      unsigned u0 = __float_as_uint(p[2*i])   + 0x8000u;
      unsigned u1 = __float_as_uint(p[2*i+1]) + 0x8000u;
      wd[i] = (u0 >> 16) | (u1 & 0xFFFF0000u);
    }
  };
  auto pvstep = [&](unsigned* wd, const char* Vb, int mt){
    uint2v s02 = __builtin_amdgcn_permlane32_swap(wd[0], wd[2], false, false);
    uint2v s13 = __builtin_amdgcn_permlane32_swap(wd[1], wd[3], false, false);
    uint2v s46 = __builtin_amdgcn_permlane32_swap(wd[4], wd[6], false, false);
    uint2v s57 = __builtin_amdgcn_permlane32_swap(wd[5], wd[7], false, false);
    union { unsigned u[4]; bf16x8 v; } pa0, pa1;
    pa0.u[0] = s02[0]; pa0.u[1] = s13[0]; pa0.u[2] = s02[1]; pa0.u[3] = s13[1];
    pa1.u[0] = s46[0]; pa1.u[1] = s57[0]; pa1.u[2] = s46[1]; pa1.u[3] = s57[1];
    int d = lq;
    bf16x8 v0 = *(const bf16x8*)(Vb + d*128 + (((mt*4 + hi)     ^ (d & 7)) << 4));
    bf16x8 v1 = *(const bf16x8*)(Vb + d*128 + (((mt*4 + 2 + hi) ^ (d & 7)) << 4));
    O = mfma32(pa0.v, v0, O);
    O = mfma32(pa1.v, v1, O);
  };
  auto computeTile = [&](const char* Kb, const char* Vb){
    const int k0 = lq, k1 = 32 + lq;
    bf16x8 a00 = *(const bf16x8*)(Kb + k0*64 + (((hi)     ^ (k0 & 3)) << 4));
    bf16x8 a01 = *(const bf16x8*)(Kb + k0*64 + (((2 + hi) ^ (k0 & 3)) << 4));
    f32x16 st0 = mfma32(a00, bq0, z16);
    st0 = mfma32(a01, bq1, st0);
    bf16x8 a10 = *(const bf16x8*)(Kb + k1*64 + (((hi)     ^ (k1 & 3)) << 4));
    bf16x8 a11 = *(const bf16x8*)(Kb + k1*64 + (((2 + hi) ^ (k1 & 3)) << 4));
    f32x16 st1 = mfma32(a10, bq0, z16);
    st1 = mfma32(a11, bq1, st1);
    unsigned wd0[8], wd1[8];
    sm_pack(st0, wd0);
    sm_pack(st1, wd1);
    pvstep(wd0, Vb, 0);
    pvstep(wd1, Vb, 1);
  };

  if (JS == 4) {
    char* Kb = smem + w*8192;
    char* Vb = Kb + 4096;
    const int j0 = w*64;
#pragma unroll
    for (int i = 0; i < 4; ++i) stageK(Kb, j0, i*64 + lane);
#pragma unroll
    for (int i = 0; i < 4; ++i) stageV(Vb, j0, i*64 + lane);
    __syncthreads();
    computeTile(Kb, Vb);
    float lw = l + __shfl_xor(l, 32);
    __syncthreads();
    float* F = (float*)smem;
#pragma unroll
    for (int r = 0; r < 16; ++r) F[(w*16 + r)*64 + lane] = O[r];
    if (hi == 0) F[4096 + w*32 + lq] = lw;
    __syncthreads();
    if (w == 0) {
      float lt = F[4096 + lq] + F[4096 + 32 + lq] + F[4096 + 64 + lq] + F[4096 + 96 + lq];
      float linv = 1.f / lt;
#pragma unroll
      for (int r = 0; r < 16; ++r) {
        float s = F[r*64 + lane] + F[(16 + r)*64 + lane] +
                  F[(32 + r)*64 + lane] + F[(48 + r)*64 + lane];
        int qr = (r & 3) + 8*(r >> 2) + 4*hi;
        float li = __shfl(linv, qr);
        o[(size_t)(b*S + q0 + qr)*128 + h*32 + lq] = f2bf(s*li);
      }
    }
  } else {
    char* K0 = smem, *V0 = smem + 4096, *K1 = smem + 8192, *V1 = smem + 12288;
    stageK(K0, 0, tid);
    stageV(V0, 0, tid);
    const int NT = S/64;
    for (int t = 0; t < NT; ++t) {
      __syncthreads();
      if (t + 1 < NT) {
        char* Kb = (t & 1) ? K0 : K1;
        char* Vb = (t & 1) ? V0 : V1;
        stageK(Kb, (t + 1)*64, tid);
        stageV(Vb, (t + 1)*64, tid);
      }
      computeTile((t & 1) ? K1 : K0, (t & 1) ? V1 : V0);
    }
    float ltot = l + __shfl_xor(l, 32);
    float linv = 1.f / ltot;
#pragma unroll
    for (int r = 0; r < 16; ++r) {
      int qr = (r & 3) + 8*(r >> 2) + 4*hi;
      float li = __shfl(linv, qr);
      o[(size_t)(b*S + q0 + qr)*128 + h*32 + lq] = f2bf(O[r]*li);
    }
  }
}

// ---------------------------------------------------------------------------
// fp32 -> bf16 cast (image + all weights)
// ---------------------------------------------------------------------------
struct CastArgs {
  const float* src[11];
  ushort_t* dst[11];
  int start[11];
};
__global__ __launch_bounds__(256) void cast_all(CastArgs a, int total8){
  int i = blockIdx.x*256 + threadIdx.x;
  if (i >= total8) return;
  int s = 0;
#pragma unroll
  for (int k = 1; k < 11; ++k) if (i >= a.start[k]) s = k;
  int off = (i - a.start[s]) * 8;
  const float* sp = a.src[s] + off;
  float4 f0 = *(const float4*)sp;
  float4 f1 = *(const float4*)(sp + 4);
  bf16x8 r;
  r[0]=(short)f2bf(f0.x); r[1]=(short)f2bf(f0.y); r[2]=(short)f2bf(f0.z); r[3]=(short)f2bf(f0.w);
  r[4]=(short)f2bf(f1.x); r[5]=(short)f2bf(f1.y); r[6]=(short)f2bf(f1.z); r[7]=(short)f2bf(f1.w);
  *(bf16x8*)(a.dst[s] + off) = r;
}

// ---------------------------------------------------------------------------
// gather / fill / scatter (bf16 tokens)
// ---------------------------------------------------------------------------
__global__ __launch_bounds__(256) void gather_k(const ushort_t* __restrict__ tok,
    const int* __restrict__ vis, ushort_t* __restrict__ xe){
  int i = blockIdx.x*256 + threadIdx.x;
  int r = i >> 4, e = (i & 15)*8;
  int b = r >> 8;
  int p = vis[r];
  *(bf16x8*)(xe + (size_t)r*128 + e) = *(const bf16x8*)(tok + ((size_t)b*1024 + p)*128 + e);
}

__global__ __launch_bounds__(256) void fill_k(const float* __restrict__ mask_tok,
    const float* __restrict__ pos, ushort_t* __restrict__ full){
  int i = blockIdx.x*256 + threadIdx.x;
  int off0 = i*8;
  int d = off0 & 127;
  int p = (off0 >> 7) & 1023;
  float4 m0 = *(const float4*)(mask_tok + d);
  float4 m1 = *(const float4*)(mask_tok + d + 4);
  const float* pp = pos + (size_t)p*128 + d;
  float4 p0 = *(const float4*)pp, p1 = *(const float4*)(pp + 4);
  bf16x8 r;
  r[0]=(short)f2bf(m0.x+p0.x); r[1]=(short)f2bf(m0.y+p0.y);
  r[2]=(short)f2bf(m0.z+p0.z); r[3]=(short)f2bf(m0.w+p0.w);
  r[4]=(short)f2bf(m1.x+p1.x); r[5]=(short)f2bf(m1.y+p1.y);
  r[6]=(short)f2bf(m1.z+p1.z); r[7]=(short)f2bf(m1.w+p1.w);
  *(bf16x8*)(full + off0) = r;
}

__global__ __launch_bounds__(256) void scatter_k(const ushort_t* __restrict__ enc,
    const int* __restrict__ vis, const float* __restrict__ pos, ushort_t* __restrict__ full){
  int i = blockIdx.x*256 + threadIdx.x;
  int r = i >> 4, e = (i & 15)*8;
  int b = r >> 8;
  int p = vis[r];
  bf16x8 ev = *(const bf16x8*)(enc + (size_t)r*128 + e);
  const float* pp = pos + (size_t)p*128 + e;
  float4 p0 = *(const float4*)pp, p1 = *(const float4*)(pp + 4);
  bf16x8 out;
  out[0]=(short)f2bf(bf2f((ushort_t)ev[0]) + p0.x);
  out[1]=(short)f2bf(bf2f((ushort_t)ev[1]) + p0.y);
  out[2]=(short)f2bf(bf2f((ushort_t)ev[2]) + p0.z);
  out[3]=(short)f2bf(bf2f((ushort_t)ev[3]) + p0.w);
  out[4]=(short)f2bf(bf2f((ushort_t)ev[4]) + p1.x);
  out[5]=(short)f2bf(bf2f((ushort_t)ev[5]) + p1.y);
  out[6]=(short)f2bf(bf2f((ushort_t)ev[6]) + p1.z);
  out[7]=(short)f2bf(bf2f((ushort_t)ev[7]) + p1.w);
  *(bf16x8*)(full + ((size_t)b*1024 + p)*128 + e) = out;
}

// ---------------------------------------------------------------------------
// Host orchestration
// ---------------------------------------------------------------------------
extern "C" void kernel_launch(void* const* d_in, const int* in_sizes, int n_in,
                              void* d_out, int out_size, void* d_ws, size_t ws_size,
                              hipStream_t stream)
{
  const float* x        = (const float*)d_in[0];
  const int*   vis      = (const int*)d_in[1];
  const float* b_patch  = (const float*)d_in[3];
  const float* mask_tok = (const float*)d_in[4];
  const float* pos      = (const float*)d_in[5];
  const float* b_recon  = (const float*)d_in[7];
  float* out = (float*)d_out;
  const float QS = 0.17677669529663687f;   // 1/sqrt(32), folded into q

  ushort_t* ws    = (ushort_t*)d_ws;
  ushort_t* tok   = ws;                     // 16384x128
  ushort_t* xe    = tok  + 2097152;         // 4096x128
  ushort_t* qkvb  = xe   + 524288;          // 16384x512
  ushort_t* obuf  = qkvb + 8388608;         // 16384x128
  ushort_t* tbuf  = obuf + 2097152;         // (unused, kept for layout)
  ushort_t* xbf   = tbuf + 2097152;         // bf16 image
  ushort_t* wbf   = xbf  + 12582912;        // bf16 weights

  ushort_t* w_qkv_e = wbf;
  ushort_t* w_out_e = w_qkv_e + 294912;
  ushort_t* w_ff1_e = w_out_e + 98304;
  ushort_t* w_ff2_e = w_ff1_e + 393216;
  ushort_t* w_qkv_d = w_ff2_e + 393216;
  ushort_t* w_out_d = w_qkv_d + 98304;
  ushort_t* w_ff1_d = w_out_d + 32768;
  ushort_t* w_ff2_d = w_ff1_d + 131072;
  ushort_t* w_pat   = w_ff2_d + 131072;
  ushort_t* w_rec   = w_pat   + 98304;
  ushort_t* vT      = w_rec   + 98304;      // [16][4][32][S<=1024]

  CastArgs ca;
  const float* srcs[11] = {x, (const float*)d_in[8], (const float*)d_in[10],
                           (const float*)d_in[14], (const float*)d_in[16],
                           (const float*)d_in[20], (const float*)d_in[22],
                           (const float*)d_in[26], (const float*)d_in[28],
                           (const float*)d_in[2], (const float*)d_in[6]};
  ushort_t* dsts[11] = {xbf, w_qkv_e, w_out_e, w_ff1_e, w_ff2_e,
                        w_qkv_d, w_out_d, w_ff1_d, w_ff2_d, w_pat, w_rec};
  int sizes[11] = {12582912, 294912, 98304, 393216, 393216,
                   98304, 32768, 131072, 131072, 98304, 98304};
  int acc8 = 0;
  for (int k = 0; k < 11; ++k){ ca.src[k]=srcs[k]; ca.dst[k]=dsts[k]; ca.start[k]=acc8; acc8 += sizes[k]/8; }
  cast_all<<<dim3((acc8 + 255)/256), 256, 0, stream>>>(ca, acc8);

  // patch embed (fused Unfold gather) -> tok [16384,128]
  mfma_gemm<64,2,1,0><<<dim3(2,256), 256, 0, stream>>>(xbf, w_pat, b_patch, tok, 16384, 128, 768, nullptr, 0, 1.f);
  gather_k<<<dim3(256), 256, 0, stream>>>(tok, vis, xe);

  for (int L = 0; L < 6; ++L) {
    const float* qb  = (const float*)d_in[9]  + L*384;
    const float* ob  = (const float*)d_in[11] + L*128;
    const float* l1w = (const float*)d_in[12] + L*128;
    const float* l1b = (const float*)d_in[13] + L*128;
    const float* f1b = (const float*)d_in[15] + L*512;
    const float* f2b = (const float*)d_in[17] + L*128;
    const float* l2w = (const float*)d_in[18] + L*128;
    const float* l2b = (const float*)d_in[19] + L*128;
    mfma_gemm<64,2,0,3><<<dim3(6,64), 256, 0, stream>>>(xe, w_qkv_e + L*49152, qb, qkvb, 4096, 384, 128, vT, 8, QS);
    attn32<256,4><<<dim3(512), 256, 0, stream>>>(qkvb, vT, obuf);
    gemm_ln<128><<<dim3(128), 256, 0, stream>>>(obuf, w_out_e + L*16384, ob, xe, l1w, l1b);
    ffn_ln<<<dim3(128), 256, 0, stream>>>(xe, w_ff1_e + L*65536, f1b, w_ff2_e + L*65536, f2b, l2w, l2b);
  }

  fill_k<<<dim3(1024), 256, 0, stream>>>(mask_tok, pos, tok);
  scatter_k<<<dim3(256), 256, 0, stream>>>(xe, vis, pos, tok);

  for (int L = 0; L < 2; ++L) {
    const float* qb  = (const float*)d_in[21] + L*384;
    const float* ob  = (const float*)d_in[23] + L*128;
    const float* l1w = (const float*)d_in[24] + L*128;
    const float* l1b = (const float*)d_in[25] + L*128;
    const float* f1b = (const float*)d_in[27] + L*512;
    const float* f2b = (const float*)d_in[29] + L*128;
    const float* l2w = (const float*)d_in[30] + L*128;
    const float* l2b = (const float*)d_in[31] + L*128;
    mfma_gemm<128,4,0,3><<<dim3(3,128), 256, 0, stream>>>(tok, w_qkv_d + L*49152, qb, qkvb, 16384, 384, 128, vT, 10, QS);
    attn32<1024,1><<<dim3(512), 256, 0, stream>>>(qkvb, vT, obuf);
    gemm_ln<128><<<dim3(512), 256, 0, stream>>>(obuf, w_out_d + L*16384, ob, tok, l1w, l1b);
    ffn_ln<<<dim3(512), 256, 0, stream>>>(tok, w_ff1_d + L*65536, f1b, w_ff2_d + L*65536, f2b, l2w, l2b);
  }

  // recon + fused unpatchify (fp32 out)
  mfma_gemm<128,4,0,2><<<dim3(6,128), 256, 0, stream>>>(tok, w_rec, b_recon, out, 16384, 768, 128, nullptr, 0, 1.f);
}

// Round 5
// 341.144 us; speedup vs baseline: 1.1729x; 1.1729x over previous
//
#include <hip/hip_runtime.h>
#include <math.h>

// B=16, C=3, H=W=512, P=16, D=128, NH=4, hd=32, GH=GW=32, NP=1024, PD=768, NV=256, FF=512
typedef unsigned short ushort_t;
typedef __attribute__((ext_vector_type(8))) short bf16x8;
typedef __attribute__((ext_vector_type(4))) float f32x4;
typedef __attribute__((ext_vector_type(16))) float f32x16;
typedef __attribute__((ext_vector_type(2))) unsigned uint2v;

__device__ __forceinline__ ushort_t f2bf(float f){
  union{float f; unsigned u;} v; v.f = f;
  unsigned r = v.u + 0x7FFFu + ((v.u >> 16) & 1u);
  return (ushort_t)(r >> 16);
}
__device__ __forceinline__ float bf2f(ushort_t h){
  union{unsigned u; float f;} v; v.u = ((unsigned)h) << 16; return v.f;
}
__device__ __forceinline__ float gelu_exact(float v){
  return 0.5f * v * (1.f + erff(v * 0.70710678118654752f));
}
#define GLD16(gp, lp) __builtin_amdgcn_global_load_lds( \
    (const __attribute__((address_space(1))) void*)(gp), \
    (__attribute__((address_space(3))) void*)(lp), 16, 0, 0)

static __device__ __forceinline__ f32x4 mfma16(bf16x8 a, bf16x8 b, f32x4 c){
  return __builtin_amdgcn_mfma_f32_16x16x32_bf16(a, b, c, 0, 0, 0);
}
static __device__ __forceinline__ f32x16 mfma32(bf16x8 a, bf16x8 b, f32x16 c){
  return __builtin_amdgcn_mfma_f32_32x32x16_bf16(a, b, c, 0, 0, 0);
}

// ---------------------------------------------------------------------------
// bf16 MFMA GEMM (LDS-staged): used for patch embed, qkv0, recon.
// SRC: 0 = plain A, 1 = patchify gather. EPI: 0 = bf16 out, 2 = fp32
// unpatchify scatter, 3 = qkv (q scaled, v transposed to vT).
// ---------------------------------------------------------------------------
template<int BT, int MI, int SRC, int EPI>
__global__ __launch_bounds__(256) void mfma_gemm(
    const ushort_t* __restrict__ A, const ushort_t* __restrict__ W,
    const float* __restrict__ bias, void* __restrict__ Cout,
    int M, int N, int K, ushort_t* __restrict__ vT, int slog, float qs)
{
  __shared__ ushort_t smem[BT*64 + BT*64];
  ushort_t* Al = smem;
  ushort_t* Wl = smem + BT*64;
  const int tid = threadIdx.x;
  const int lane = tid & 63, w = tid >> 6;
  const int wr = w >> 1, wc = w & 1;
  const int g = lane >> 4, lq = lane & 15;
  const int m0 = blockIdx.y * BT, n0 = blockIdx.x * BT;

  const f32x4 zf = {0.f, 0.f, 0.f, 0.f};
  f32x4 acc[MI][MI];
#pragma unroll
  for (int i = 0; i < MI; ++i)
#pragma unroll
    for (int j = 0; j < MI; ++j) acc[i][j] = zf;

  float bv[MI];
#pragma unroll
  for (int ni = 0; ni < MI; ++ni) bv[ni] = bias[n0 + wc*(BT/2) + ni*16 + lq];

  const int KT = K >> 6;
  for (int kt = 0; kt < KT; ++kt) {
    if (kt) __syncthreads();
    const int k0 = kt << 6;
#pragma unroll
    for (int i = 0; i < BT/32; ++i) {
      int chunk = i*256 + tid;
      int row = chunk >> 3, c = chunk & 7;
      int kk = k0 + ((c ^ (row & 7)) << 3);
      const ushort_t* src;
      if (SRC == 0) {
        src = A + (size_t)(m0 + row) * K + kk;
      } else {
        int gm = m0 + row;
        int bb = gm >> 10, pp = gm & 1023, gh = pp >> 5, gw = pp & 31;
        int ci = kk >> 8, rem = kk & 255, py = rem >> 4, px = rem & 15;
        src = A + ((size_t)((bb*3 + ci)*512 + gh*16 + py) * 512 + gw*16 + px);
      }
      GLD16(src, (char*)Al + chunk*16);
    }
#pragma unroll
    for (int i = 0; i < BT/32; ++i) {
      int chunk = i*256 + tid;
      int row = chunk >> 3, c = chunk & 7;
      int kk = k0 + ((c ^ (row & 7)) << 3);
      GLD16(W + (size_t)(n0 + row) * K + kk, (char*)Wl + chunk*16);
    }
    __syncthreads();
#pragma unroll
    for (int ks = 0; ks < 2; ++ks) {
      bf16x8 af[MI], bfr[MI];
#pragma unroll
      for (int mi = 0; mi < MI; ++mi) {
        int row = wr*(BT/2) + mi*16 + lq;
        int c = (ks*4 + g) ^ (row & 7);
        af[mi] = *(const bf16x8*)((const char*)Al + row*128 + c*16);
      }
#pragma unroll
      for (int ni = 0; ni < MI; ++ni) {
        int row = wc*(BT/2) + ni*16 + lq;
        int c = (ks*4 + g) ^ (row & 7);
        bfr[ni] = *(const bf16x8*)((const char*)Wl + row*128 + c*16);
      }
#pragma unroll
      for (int mi = 0; mi < MI; ++mi)
#pragma unroll
        for (int ni = 0; ni < MI; ++ni)
          acc[mi][ni] = mfma16(af[mi], bfr[ni], acc[mi][ni]);
    }
  }

  if (EPI == 3 && n0 >= 256) {
    const int Sm1 = (1 << slog) - 1;
#pragma unroll
    for (int mi = 0; mi < MI; ++mi) {
      int gm0 = m0 + wr*(BT/2) + mi*16 + g*4;
      int bb = gm0 >> slog, s0 = gm0 & Sm1;
#pragma unroll
      for (int ni = 0; ni < MI; ++ni) {
        int n = n0 + wc*(BT/2) + ni*16 + lq;
        int vcol = n - 256, hh = vcol >> 5, dd = vcol & 31;
        unsigned pw0 = ((unsigned)f2bf(acc[mi][ni][0] + bv[ni])) |
                       (((unsigned)f2bf(acc[mi][ni][1] + bv[ni])) << 16);
        unsigned pw1 = ((unsigned)f2bf(acc[mi][ni][2] + bv[ni])) |
                       (((unsigned)f2bf(acc[mi][ni][3] + bv[ni])) << 16);
        uint2 pk; pk.x = pw0; pk.y = pw1;
        *(uint2*)(vT + (((size_t)(bb*4 + hh)*32 + dd) << slog) + s0) = pk;
      }
    }
    return;
  }

  if (EPI == 2) {
    float* img = (float*)Cout;
#pragma unroll
    for (int mi = 0; mi < MI; ++mi) {
#pragma unroll
      for (int r = 0; r < 4; ++r) {
        int gm = m0 + wr*(BT/2) + mi*16 + g*4 + r;
        int bb = gm >> 10, pp = gm & 1023, gh = pp >> 5, gw = pp & 31;
#pragma unroll
        for (int ni = 0; ni < MI; ++ni) {
          int n = n0 + wc*(BT/2) + ni*16 + lq;
          int ci = n >> 8, rem = n & 255, py = rem >> 4, px = rem & 15;
          img[(size_t)((bb*3 + ci)*512 + gh*16 + py)*512 + gw*16 + px] =
              acc[mi][ni][r] + bv[ni];
        }
      }
    }
  } else {
    const float cs = (EPI == 3 && n0 < 128) ? qs : 1.0f;
    __syncthreads();
    constexpr int CPR = BT/8;
#pragma unroll
    for (int mi = 0; mi < MI; ++mi)
#pragma unroll
      for (int ni = 0; ni < MI; ++ni)
#pragma unroll
        for (int r = 0; r < 4; ++r) {
          int row = wr*(BT/2) + mi*16 + g*4 + r;
          int col = wc*(BT/2) + ni*16 + lq;
          float v = acc[mi][ni][r] + bv[ni];
          if (EPI == 3) v *= cs;
          int cc = (col >> 3) ^ (row & (CPR-1));
          smem[row*BT + cc*8 + (col & 7)] = f2bf(v);
        }
    __syncthreads();
    ushort_t* Co = (ushort_t*)Cout;
#pragma unroll
    for (int i = 0; i < BT*BT/2048; ++i) {
      int chunk = i*256 + tid;
      int row = chunk / CPR, cc = chunk % CPR;
      int c = cc ^ (row & (CPR-1));
      bf16x8 v = *(const bf16x8*)((const char*)smem + chunk*16);
      *(bf16x8*)(Co + (size_t)(m0+row)*N + n0 + c*8) = v;
    }
  }
}

// ---------------------------------------------------------------------------
// MEGA layer-tail kernel: out-proj + LN1 + FFN(GELU) + LN2 [+ next qkv].
// All GEMMs load A/W fragments DIRECTLY global->register (K<=512, weights
// L2-hot): zero staging barriers. LDS only for X'/H handoff + LN reduce.
// MI2 = rows/16 per block (1 or 2); 4 waves N-split.
// ---------------------------------------------------------------------------
template<int MI2, int QKV>
__global__ __launch_bounds__(256) void mega_mlp(
    const ushort_t* __restrict__ Ao, const ushort_t* __restrict__ Wo,
    const float* __restrict__ bo, ushort_t* __restrict__ X,
    const float* __restrict__ l1w, const float* __restrict__ l1b,
    const ushort_t* __restrict__ W1, const float* __restrict__ b1,
    const ushort_t* __restrict__ W2, const float* __restrict__ b2,
    const float* __restrict__ l2w, const float* __restrict__ l2b,
    const ushort_t* __restrict__ Wq, const float* __restrict__ bq,
    ushort_t* __restrict__ qkvb, ushort_t* __restrict__ vT,
    int slog, float qs)
{
  constexpr int BM = MI2 * 16;
  constexpr int TB = BM * 128;              // bytes per 64-k LDS tile
  __shared__ __align__(16) ushort_t Xl[2*BM*64];
  __shared__ __align__(16) ushort_t Hl[8*BM*64];
  __shared__ float red[2][BM][4];
  const int tid = threadIdx.x, lane = tid & 63, w = tid >> 6;
  const int g = lane >> 4, lq = lane & 15;
  const int m0 = blockIdx.x * BM;
  const f32x4 zf = {0.f,0.f,0.f,0.f};

  // ---- P1: out-projection (K=128), direct-register ----
  f32x4 acc[MI2][2];
#pragma unroll
  for (int mi = 0; mi < MI2; ++mi) { acc[mi][0] = zf; acc[mi][1] = zf; }
  {
    bf16x8 a[MI2][4], b[2][4];
#pragma unroll
    for (int mi = 0; mi < MI2; ++mi)
#pragma unroll
      for (int kf = 0; kf < 4; ++kf)
        a[mi][kf] = *(const bf16x8*)(Ao + (size_t)(m0 + mi*16 + lq)*128 + kf*32 + g*8);
#pragma unroll
    for (int ni = 0; ni < 2; ++ni)
#pragma unroll
      for (int kf = 0; kf < 4; ++kf)
        b[ni][kf] = *(const bf16x8*)(Wo + (size_t)(w*32 + ni*16 + lq)*128 + kf*32 + g*8);
#pragma unroll
    for (int kf = 0; kf < 4; ++kf)
#pragma unroll
      for (int mi = 0; mi < MI2; ++mi)
#pragma unroll
        for (int ni = 0; ni < 2; ++ni)
          acc[mi][ni] = mfma16(a[mi][kf], b[ni][kf], acc[mi][ni]);
  }

  // ---- LN1 (cross-wave reduce), keep X' in regs, write X global + Xl ----
  float xp[MI2][2][4];
  {
    float bv[2], lwv[2], lbv[2];
#pragma unroll
    for (int ni = 0; ni < 2; ++ni) {
      int col = w*32 + ni*16 + lq;
      bv[ni] = bo[col]; lwv[ni] = l1w[col]; lbv[ni] = l1b[col];
    }
#pragma unroll
    for (int mi = 0; mi < MI2; ++mi)
#pragma unroll
      for (int r = 0; r < 4; ++r) {
        int row = m0 + mi*16 + g*4 + r;
#pragma unroll
        for (int ni = 0; ni < 2; ++ni) {
          int col = w*32 + ni*16 + lq;
          xp[mi][ni][r] = acc[mi][ni][r] + bv[ni] + bf2f(X[(size_t)row*128 + col]);
        }
        float s = xp[mi][0][r] + xp[mi][1][r];
        float q = xp[mi][0][r]*xp[mi][0][r] + xp[mi][1][r]*xp[mi][1][r];
        s += __shfl_xor(s,1); s += __shfl_xor(s,2); s += __shfl_xor(s,4); s += __shfl_xor(s,8);
        q += __shfl_xor(q,1); q += __shfl_xor(q,2); q += __shfl_xor(q,4); q += __shfl_xor(q,8);
        if (lq == 0) { red[0][mi*16+g*4+r][w] = s; red[1][mi*16+g*4+r][w] = q; }
      }
    __syncthreads();
#pragma unroll
    for (int mi = 0; mi < MI2; ++mi)
#pragma unroll
      for (int r = 0; r < 4; ++r) {
        int rl = mi*16 + g*4 + r;
        float s = red[0][rl][0]+red[0][rl][1]+red[0][rl][2]+red[0][rl][3];
        float q = red[1][rl][0]+red[1][rl][1]+red[1][rl][2]+red[1][rl][3];
        float mean = s * 0.0078125f;
        float var = q * 0.0078125f - mean*mean;
        float rstd = rsqrtf(var + 1e-5f);
#pragma unroll
        for (int ni = 0; ni < 2; ++ni) {
          int col = w*32 + ni*16 + lq;
          float val = (xp[mi][ni][r]-mean)*rstd*lwv[ni] + lbv[ni];
          xp[mi][ni][r] = val;
          ushort_t hv = f2bf(val);
          X[(size_t)(m0+rl)*128 + col] = hv;
          int kt = col >> 6, hc = (col & 63) >> 3, he = col & 7;
          *(ushort_t*)((char*)Xl + kt*TB + rl*128 + ((hc ^ (rl & 7)) << 4) + he*2) = hv;
        }
      }
  }
  __syncthreads();

  // ---- P2: ff1 + GELU -> Hl (A from Xl, W1 direct) ----
  bf16x8 a2[MI2][4];
#pragma unroll
  for (int mi = 0; mi < MI2; ++mi)
#pragma unroll
    for (int kf = 0; kf < 4; ++kf) {
      int kt = kf >> 1, ks = kf & 1, row = mi*16 + lq;
      int c = (ks*4 + g) ^ (row & 7);
      a2[mi][kf] = *(const bf16x8*)((const char*)Xl + kt*TB + row*128 + c*16);
    }
#pragma unroll
  for (int hp = 0; hp < 4; ++hp) {
    f32x4 acc1[MI2][2];
#pragma unroll
    for (int mi = 0; mi < MI2; ++mi) { acc1[mi][0] = zf; acc1[mi][1] = zf; }
    bf16x8 b1f[2][4];
#pragma unroll
    for (int ni = 0; ni < 2; ++ni)
#pragma unroll
      for (int kf = 0; kf < 4; ++kf)
        b1f[ni][kf] = *(const bf16x8*)(W1 + (size_t)(hp*128 + w*32 + ni*16 + lq)*128 + kf*32 + g*8);
#pragma unroll
    for (int kf = 0; kf < 4; ++kf)
#pragma unroll
      for (int mi = 0; mi < MI2; ++mi)
#pragma unroll
        for (int ni = 0; ni < 2; ++ni)
          acc1[mi][ni] = mfma16(a2[mi][kf], b1f[ni][kf], acc1[mi][ni]);
#pragma unroll
    for (int ni = 0; ni < 2; ++ni) {
      int hid = hp*128 + w*32 + ni*16 + lq;
      float bb = b1[hid];
      int hkt = hid >> 6, hc = (hid & 63) >> 3, he = hid & 7;
#pragma unroll
      for (int mi = 0; mi < MI2; ++mi)
#pragma unroll
        for (int r = 0; r < 4; ++r) {
          int mrow = mi*16 + g*4 + r;
          float hv = gelu_exact(acc1[mi][ni][r] + bb);
          *(ushort_t*)((char*)Hl + hkt*TB + mrow*128 + ((hc ^ (mrow & 7)) << 4) + he*2) = f2bf(hv);
        }
    }
  }
  __syncthreads();

  // ---- P3: ff2 (K=512, A from Hl, W2 direct) ----
  f32x4 acc2[MI2][2];
#pragma unroll
  for (int mi = 0; mi < MI2; ++mi) { acc2[mi][0] = zf; acc2[mi][1] = zf; }
#pragma unroll
  for (int kf = 0; kf < 16; ++kf) {
    int kt = kf >> 1, ks = kf & 1;
    bf16x8 af[MI2], bfr[2];
#pragma unroll
    for (int mi = 0; mi < MI2; ++mi) {
      int row = mi*16 + lq, c = (ks*4 + g) ^ (row & 7);
      af[mi] = *(const bf16x8*)((const char*)Hl + kt*TB + row*128 + c*16);
    }
#pragma unroll
    for (int ni = 0; ni < 2; ++ni)
      bfr[ni] = *(const bf16x8*)(W2 + (size_t)(w*32 + ni*16 + lq)*512 + kf*32 + g*8);
#pragma unroll
    for (int mi = 0; mi < MI2; ++mi)
#pragma unroll
      for (int ni = 0; ni < 2; ++ni)
        acc2[mi][ni] = mfma16(af[mi], bfr[ni], acc2[mi][ni]);
  }

  // ---- LN2 (residual = xp regs), write X global [+ Xl for qkv] ----
  {
    float bv[2], lwv[2], lbv[2];
#pragma unroll
    for (int ni = 0; ni < 2; ++ni) {
      int col = w*32 + ni*16 + lq;
      bv[ni] = b2[col]; lwv[ni] = l2w[col]; lbv[ni] = l2b[col];
    }
#pragma unroll
    for (int mi = 0; mi < MI2; ++mi)
#pragma unroll
      for (int r = 0; r < 4; ++r) {
#pragma unroll
        for (int ni = 0; ni < 2; ++ni)
          xp[mi][ni][r] = acc2[mi][ni][r] + bv[ni] + xp[mi][ni][r];
        float s = xp[mi][0][r] + xp[mi][1][r];
        float q = xp[mi][0][r]*xp[mi][0][r] + xp[mi][1][r]*xp[mi][1][r];
        s += __shfl_xor(s,1); s += __shfl_xor(s,2); s += __shfl_xor(s,4); s += __shfl_xor(s,8);
        q += __shfl_xor(q,1); q += __shfl_xor(q,2); q += __shfl_xor(q,4); q += __shfl_xor(q,8);
        if (lq == 0) { red[0][mi*16+g*4+r][w] = s; red[1][mi*16+g*4+r][w] = q; }
      }
    __syncthreads();
#pragma unroll
    for (int mi = 0; mi < MI2; ++mi)
#pragma unroll
      for (int r = 0; r < 4; ++r) {
        int rl = mi*16 + g*4 + r;
        float s = red[0][rl][0]+red[0][rl][1]+red[0][rl][2]+red[0][rl][3];
        float q = red[1][rl][0]+red[1][rl][1]+red[1][rl][2]+red[1][rl][3];
        float mean = s * 0.0078125f;
        float var = q * 0.0078125f - mean*mean;
        float rstd = rsqrtf(var + 1e-5f);
#pragma unroll
        for (int ni = 0; ni < 2; ++ni) {
          int col = w*32 + ni*16 + lq;
          float val = (xp[mi][ni][r]-mean)*rstd*lwv[ni] + lbv[ni];
          ushort_t hv = f2bf(val);
          X[(size_t)(m0+rl)*128 + col] = hv;
          if (QKV) {
            int kt = col >> 6, hc = (col & 63) >> 3, he = col & 7;
            *(ushort_t*)((char*)Xl + kt*TB + rl*128 + ((hc ^ (rl & 7)) << 4) + he*2) = hv;
          }
        }
      }
  }

  // ---- P4: next layer's qkv (N=384, A from Xl, Wq direct) ----
  if (QKV) {
    __syncthreads();
    bf16x8 a3[MI2][4];
#pragma unroll
    for (int mi = 0; mi < MI2; ++mi)
#pragma unroll
      for (int kf = 0; kf < 4; ++kf) {
        int kt = kf >> 1, ks = kf & 1, row = mi*16 + lq;
        int c = (ks*4 + g) ^ (row & 7);
        a3[mi][kf] = *(const bf16x8*)((const char*)Xl + kt*TB + row*128 + c*16);
      }
    const int Sm1 = (1 << slog) - 1;
#pragma unroll
    for (int ni = 0; ni < 6; ++ni) {
      int nb = w*96 + ni*16;
      int col = nb + lq;
      f32x4 aq[MI2];
#pragma unroll
      for (int mi = 0; mi < MI2; ++mi) aq[mi] = zf;
      bf16x8 bq8[4];
#pragma unroll
      for (int kf = 0; kf < 4; ++kf)
        bq8[kf] = *(const bf16x8*)(Wq + (size_t)col*128 + kf*32 + g*8);
#pragma unroll
      for (int kf = 0; kf < 4; ++kf)
#pragma unroll
        for (int mi = 0; mi < MI2; ++mi)
          aq[mi] = mfma16(a3[mi][kf], bq8[kf], aq[mi]);
      float bias = bq[col];
      if (col < 256) {
        float sc = (col < 128) ? qs : 1.f;
#pragma unroll
        for (int mi = 0; mi < MI2; ++mi)
#pragma unroll
          for (int r = 0; r < 4; ++r) {
            int row = m0 + mi*16 + g*4 + r;
            qkvb[(size_t)row*384 + col] = f2bf((aq[mi][r] + bias)*sc);
          }
      } else {
        int vcol = col - 256, hh = vcol >> 5, dd = vcol & 31;
#pragma unroll
        for (int mi = 0; mi < MI2; ++mi) {
          int gm0 = m0 + mi*16 + g*4;
          int bb = gm0 >> slog, s0 = gm0 & Sm1;
          unsigned pw0 = ((unsigned)f2bf(aq[mi][0] + bias)) |
                         (((unsigned)f2bf(aq[mi][1] + bias)) << 16);
          unsigned pw1 = ((unsigned)f2bf(aq[mi][2] + bias)) |
                         (((unsigned)f2bf(aq[mi][3] + bias)) << 16);
          uint2 pk; pk.x = pw0; pk.y = pw1;
          *(uint2*)(vT + (((size_t)(bb*4 + hh)*32 + dd) << slog) + s0) = pk;
        }
      }
    }
  }
}

// ---------------------------------------------------------------------------
// 32x32 MFMA flash attention (unchanged from round 3)
// ---------------------------------------------------------------------------
template<int S, int JS>
__global__ __launch_bounds__(256) void attn32(
    const ushort_t* __restrict__ qkv, const ushort_t* __restrict__ vTg,
    ushort_t* __restrict__ o)
{
  constexpr int LDSB = (JS == 1) ? 16384 : 32768;
  __shared__ __align__(16) char smem[LDSB];
  const int tid = threadIdx.x, lane = tid & 63, w = tid >> 6;
  const int hi = lane >> 5, lq = lane & 31;
  int lin = blockIdx.x;
  int nid = (lin & 7) * 64 + (lin >> 3);
  int bx = nid & 7, bh = nid >> 3;
  int h = bh & 3, b = bh >> 2;
  const int q0 = (JS == 1) ? (bx*128 + w*32) : (bx*32);

  bf16x8 bq0 = *(const bf16x8*)(qkv + (size_t)(b*S + q0 + lq)*384 + h*32 + hi*8);
  bf16x8 bq1 = *(const bf16x8*)(qkv + (size_t)(b*S + q0 + lq)*384 + h*32 + 16 + hi*8);

  f32x16 O;
#pragma unroll
  for (int i = 0; i < 16; ++i) O[i] = 0.f;
  const f32x16 z16 = O;
  float l = 0.f;

  auto stageK = [&](char* Kb, int j0, int ci){
    int k = ci >> 2, cp = ci & 3, c = cp ^ (k & 3);
    GLD16(qkv + (size_t)(b*S + j0 + k)*384 + 128 + h*32 + c*8, Kb + ci*16);
  };
  auto stageV = [&](char* Vb, int j0, int ci){
    int d = ci >> 3, cp = ci & 7, c = cp ^ (d & 7);
    GLD16(vTg + (size_t)(bh*32 + d)*S + j0 + c*8, Vb + ci*16);
  };

  auto sm_pack = [&](const f32x16& stv, unsigned* wd){
    float p[16];
#pragma unroll
    for (int r = 0; r < 16; ++r) { p[r] = __expf(stv[r]); l += p[r]; }
#pragma unroll
    for (int i = 0; i < 8; ++i) {
      unsigned u0 = __float_as_uint(p[2*i])   + 0x8000u;
      unsigned u1 = __float_as_uint(p[2*i+1]) + 0x8000u;
      wd[i] = (u0 >> 16) | (u1 & 0xFFFF0000u);
    }
  };
  auto pvstep = [&](unsigned* wd, const char* Vb, int mt){
    uint2v s02 = __builtin_amdgcn_permlane32_swap(wd[0], wd[2], false, false);
    uint2v s13 = __builtin_amdgcn_permlane32_swap(wd[1], wd[3], false, false);
    uint2v s46 = __builtin_amdgcn_permlane32_swap(wd[4], wd[6], false, false);
    uint2v s57 = __builtin_amdgcn_permlane32_swap(wd[5], wd[7], false, false);
    union { unsigned u[4]; bf16x8 v; } pa0, pa1;
    pa0.u[0] = s02[0]; pa0.u[1] = s13[0]; pa0.u[2] = s02[1]; pa0.u[3] = s13[1];
    pa1.u[0] = s46[0]; pa1.u[1] = s57[0]; pa1.u[2] = s46[1]; pa1.u[3] = s57[1];
    int d = lq;
    bf16x8 v0 = *(const bf16x8*)(Vb + d*128 + (((mt*4 + hi)     ^ (d & 7)) << 4));
    bf16x8 v1 = *(const bf16x8*)(Vb + d*128 + (((mt*4 + 2 + hi) ^ (d & 7)) << 4));
    O = mfma32(pa0.v, v0, O);
    O = mfma32(pa1.v, v1, O);
  };
  auto computeTile = [&](const char* Kb, const char* Vb){
    const int k0 = lq, k1 = 32 + lq;
    bf16x8 a00 = *(const bf16x8*)(Kb + k0*64 + (((hi)     ^ (k0 & 3)) << 4));
    bf16x8 a01 = *(const bf16x8*)(Kb + k0*64 + (((2 + hi) ^ (k0 & 3)) << 4));
    f32x16 st0 = mfma32(a00, bq0, z16);
    st0 = mfma32(a01, bq1, st0);
    bf16x8 a10 = *(const bf16x8*)(Kb + k1*64 + (((hi)     ^ (k1 & 3)) << 4));
    bf16x8 a11 = *(const bf16x8*)(Kb + k1*64 + (((2 + hi) ^ (k1 & 3)) << 4));
    f32x16 st1 = mfma32(a10, bq0, z16);
    st1 = mfma32(a11, bq1, st1);
    unsigned wd0[8], wd1[8];
    sm_pack(st0, wd0);
    sm_pack(st1, wd1);
    pvstep(wd0, Vb, 0);
    pvstep(wd1, Vb, 1);
  };

  if (JS == 4) {
    char* Kb = smem + w*8192;
    char* Vb = Kb + 4096;
    const int j0 = w*64;
#pragma unroll
    for (int i = 0; i < 4; ++i) stageK(Kb, j0, i*64 + lane);
#pragma unroll
    for (int i = 0; i < 4; ++i) stageV(Vb, j0, i*64 + lane);
    __syncthreads();
    computeTile(Kb, Vb);
    float lw = l + __shfl_xor(l, 32);
    __syncthreads();
    float* F = (float*)smem;
#pragma unroll
    for (int r = 0; r < 16; ++r) F[(w*16 + r)*64 + lane] = O[r];
    if (hi == 0) F[4096 + w*32 + lq] = lw;
    __syncthreads();
    if (w == 0) {
      float lt = F[4096 + lq] + F[4096 + 32 + lq] + F[4096 + 64 + lq] + F[4096 + 96 + lq];
      float linv = 1.f / lt;
#pragma unroll
      for (int r = 0; r < 16; ++r) {
        float s = F[r*64 + lane] + F[(16 + r)*64 + lane] +
                  F[(32 + r)*64 + lane] + F[(48 + r)*64 + lane];
        int qr = (r & 3) + 8*(r >> 2) + 4*hi;
        float li = __shfl(linv, qr);
        o[(size_t)(b*S + q0 + qr)*128 + h*32 + lq] = f2bf(s*li);
      }
    }
  } else {
    char* K0 = smem, *V0 = smem + 4096, *K1 = smem + 8192, *V1 = smem + 12288;
    stageK(K0, 0, tid);
    stageV(V0, 0, tid);
    const int NT = S/64;
    for (int t = 0; t < NT; ++t) {
      __syncthreads();
      if (t + 1 < NT) {
        char* Kb = (t & 1) ? K0 : K1;
        char* Vb = (t & 1) ? V0 : V1;
        stageK(Kb, (t + 1)*64, tid);
        stageV(Vb, (t + 1)*64, tid);
      }
      computeTile((t & 1) ? K1 : K0, (t & 1) ? V1 : V0);
    }
    float ltot = l + __shfl_xor(l, 32);
    float linv = 1.f / ltot;
#pragma unroll
    for (int r = 0; r < 16; ++r) {
      int qr = (r & 3) + 8*(r >> 2) + 4*hi;
      float li = __shfl(linv, qr);
      o[(size_t)(b*S + q0 + qr)*128 + h*32 + lq] = f2bf(O[r]*li);
    }
  }
}

// ---------------------------------------------------------------------------
// fp32 -> bf16 cast (image + all weights)
// ---------------------------------------------------------------------------
struct CastArgs {
  const float* src[11];
  ushort_t* dst[11];
  int start[11];
};
__global__ __launch_bounds__(256) void cast_all(CastArgs a, int total8){
  int i = blockIdx.x*256 + threadIdx.x;
  if (i >= total8) return;
  int s = 0;
#pragma unroll
  for (int k = 1; k < 11; ++k) if (i >= a.start[k]) s = k;
  int off = (i - a.start[s]) * 8;
  const float* sp = a.src[s] + off;
  float4 f0 = *(const float4*)sp;
  float4 f1 = *(const float4*)(sp + 4);
  bf16x8 r;
  r[0]=(short)f2bf(f0.x); r[1]=(short)f2bf(f0.y); r[2]=(short)f2bf(f0.z); r[3]=(short)f2bf(f0.w);
  r[4]=(short)f2bf(f1.x); r[5]=(short)f2bf(f1.y); r[6]=(short)f2bf(f1.z); r[7]=(short)f2bf(f1.w);
  *(bf16x8*)(a.dst[s] + off) = r;
}

// ---------------------------------------------------------------------------
// gather / fill / scatter (bf16 tokens)
// ---------------------------------------------------------------------------
__global__ __launch_bounds__(256) void gather_k(const ushort_t* __restrict__ tok,
    const int* __restrict__ vis, ushort_t* __restrict__ xe){
  int i = blockIdx.x*256 + threadIdx.x;
  int r = i >> 4, e = (i & 15)*8;
  int b = r >> 8;
  int p = vis[r];
  *(bf16x8*)(xe + (size_t)r*128 + e) = *(const bf16x8*)(tok + ((size_t)b*1024 + p)*128 + e);
}

__global__ __launch_bounds__(256) void fill_k(const float* __restrict__ mask_tok,
    const float* __restrict__ pos, ushort_t* __restrict__ full){
  int i = blockIdx.x*256 + threadIdx.x;
  int off0 = i*8;
  int d = off0 & 127;
  int p = (off0 >> 7) & 1023;
  float4 m0 = *(const float4*)(mask_tok + d);
  float4 m1 = *(const float4*)(mask_tok + d + 4);
  const float* pp = pos + (size_t)p*128 + d;
  float4 p0 = *(const float4*)pp, p1 = *(const float4*)(pp + 4);
  bf16x8 r;
  r[0]=(short)f2bf(m0.x+p0.x); r[1]=(short)f2bf(m0.y+p0.y);
  r[2]=(short)f2bf(m0.z+p0.z); r[3]=(short)f2bf(m0.w+p0.w);
  r[4]=(short)f2bf(m1.x+p1.x); r[5]=(short)f2bf(m1.y+p1.y);
  r[6]=(short)f2bf(m1.z+p1.z); r[7]=(short)f2bf(m1.w+p1.w);
  *(bf16x8*)(full + off0) = r;
}

__global__ __launch_bounds__(256) void scatter_k(const ushort_t* __restrict__ enc,
    const int* __restrict__ vis, const float* __restrict__ pos, ushort_t* __restrict__ full){
  int i = blockIdx.x*256 + threadIdx.x;
  int r = i >> 4, e = (i & 15)*8;
  int b = r >> 8;
  int p = vis[r];
  bf16x8 ev = *(const bf16x8*)(enc + (size_t)r*128 + e);
  const float* pp = pos + (size_t)p*128 + e;
  float4 p0 = *(const float4*)pp, p1 = *(const float4*)(pp + 4);
  bf16x8 out;
  out[0]=(short)f2bf(bf2f((ushort_t)ev[0]) + p0.x);
  out[1]=(short)f2bf(bf2f((ushort_t)ev[1]) + p0.y);
  out[2]=(short)f2bf(bf2f((ushort_t)ev[2]) + p0.z);
  out[3]=(short)f2bf(bf2f((ushort_t)ev[3]) + p0.w);
  out[4]=(short)f2bf(bf2f((ushort_t)ev[4]) + p1.x);
  out[5]=(short)f2bf(bf2f((ushort_t)ev[5]) + p1.y);
  out[6]=(short)f2bf(bf2f((ushort_t)ev[6]) + p1.z);
  out[7]=(short)f2bf(bf2f((ushort_t)ev[7]) + p1.w);
  *(bf16x8*)(full + ((size_t)b*1024 + p)*128 + e) = out;
}

// ---------------------------------------------------------------------------
// Host orchestration
// ---------------------------------------------------------------------------
extern "C" void kernel_launch(void* const* d_in, const int* in_sizes, int n_in,
                              void* d_out, int out_size, void* d_ws, size_t ws_size,
                              hipStream_t stream)
{
  const float* x        = (const float*)d_in[0];
  const int*   vis      = (const int*)d_in[1];
  const float* b_patch  = (const float*)d_in[3];
  const float* mask_tok = (const float*)d_in[4];
  const float* pos      = (const float*)d_in[5];
  const float* b_recon  = (const float*)d_in[7];
  float* out = (float*)d_out;
  const float QS = 0.17677669529663687f;   // 1/sqrt(32), folded into q

  ushort_t* ws    = (ushort_t*)d_ws;
  ushort_t* tok   = ws;                     // 16384x128
  ushort_t* xe    = tok  + 2097152;         // 4096x128
  ushort_t* qkvb  = xe   + 524288;          // 16384x512
  ushort_t* obuf  = qkvb + 8388608;         // 16384x128
  ushort_t* tbuf  = obuf + 2097152;         // (unused)
  ushort_t* xbf   = tbuf + 2097152;         // bf16 image
  ushort_t* wbf   = xbf  + 12582912;        // bf16 weights

  ushort_t* w_qkv_e = wbf;
  ushort_t* w_out_e = w_qkv_e + 294912;
  ushort_t* w_ff1_e = w_out_e + 98304;
  ushort_t* w_ff2_e = w_ff1_e + 393216;
  ushort_t* w_qkv_d = w_ff2_e + 393216;
  ushort_t* w_out_d = w_qkv_d + 98304;
  ushort_t* w_ff1_d = w_out_d + 32768;
  ushort_t* w_ff2_d = w_ff1_d + 131072;
  ushort_t* w_pat   = w_ff2_d + 131072;
  ushort_t* w_rec   = w_pat   + 98304;
  ushort_t* vT      = w_rec   + 98304;      // [16][4][32][S<=1024]

  CastArgs ca;
  const float* srcs[11] = {x, (const float*)d_in[8], (const float*)d_in[10],
                           (const float*)d_in[14], (const float*)d_in[16],
                           (const float*)d_in[20], (const float*)d_in[22],
                           (const float*)d_in[26], (const float*)d_in[28],
                           (const float*)d_in[2], (const float*)d_in[6]};
  ushort_t* dsts[11] = {xbf, w_qkv_e, w_out_e, w_ff1_e, w_ff2_e,
                        w_qkv_d, w_out_d, w_ff1_d, w_ff2_d, w_pat, w_rec};
  int sizes[11] = {12582912, 294912, 98304, 393216, 393216,
                   98304, 32768, 131072, 131072, 98304, 98304};
  int acc8 = 0;
  for (int k = 0; k < 11; ++k){ ca.src[k]=srcs[k]; ca.dst[k]=dsts[k]; ca.start[k]=acc8; acc8 += sizes[k]/8; }
  cast_all<<<dim3((acc8 + 255)/256), 256, 0, stream>>>(ca, acc8);

  // patch embed (fused Unfold gather) -> tok [16384,128]
  mfma_gemm<64,2,1,0><<<dim3(2,256), 256, 0, stream>>>(xbf, w_pat, b_patch, tok, 16384, 128, 768, nullptr, 0, 1.f);
  gather_k<<<dim3(256), 256, 0, stream>>>(tok, vis, xe);

  // encoder: qkv for layer 0, then per layer {attn, mega(+qkv_next)}
  mfma_gemm<64,2,0,3><<<dim3(6,64), 256, 0, stream>>>(xe, w_qkv_e, (const float*)d_in[9], qkvb, 4096, 384, 128, vT, 8, QS);
  for (int L = 0; L < 6; ++L) {
    const float* ob  = (const float*)d_in[11] + L*128;
    const float* l1w = (const float*)d_in[12] + L*128;
    const float* l1b = (const float*)d_in[13] + L*128;
    const float* f1b = (const float*)d_in[15] + L*512;
    const float* f2b = (const float*)d_in[17] + L*128;
    const float* l2w = (const float*)d_in[18] + L*128;
    const float* l2b = (const float*)d_in[19] + L*128;
    attn32<256,4><<<dim3(512), 256, 0, stream>>>(qkvb, vT, obuf);
    if (L < 5) {
      mega_mlp<1,1><<<dim3(256), 256, 0, stream>>>(obuf, w_out_e + L*16384, ob, xe,
          l1w, l1b, w_ff1_e + L*65536, f1b, w_ff2_e + L*65536, f2b, l2w, l2b,
          w_qkv_e + (L+1)*49152, (const float*)d_in[9] + (L+1)*384, qkvb, vT, 8, QS);
    } else {
      mega_mlp<1,0><<<dim3(256), 256, 0, stream>>>(obuf, w_out_e + L*16384, ob, xe,
          l1w, l1b, w_ff1_e + L*65536, f1b, w_ff2_e + L*65536, f2b, l2w, l2b,
          w_qkv_e, (const float*)d_in[9], qkvb, vT, 8, QS);
    }
  }

  fill_k<<<dim3(1024), 256, 0, stream>>>(mask_tok, pos, tok);
  scatter_k<<<dim3(256), 256, 0, stream>>>(xe, vis, pos, tok);

  // decoder: qkv for layer 0, then per layer {attn, mega(+qkv_next)}
  mfma_gemm<128,4,0,3><<<dim3(3,128), 256, 0, stream>>>(tok, w_qkv_d, (const float*)d_in[21], qkvb, 16384, 384, 128, vT, 10, QS);
  for (int L = 0; L < 2; ++L) {
    const float* ob  = (const float*)d_in[23] + L*128;
    const float* l1w = (const float*)d_in[24] + L*128;
    const float* l1b = (const float*)d_in[25] + L*128;
    const float* f1b = (const float*)d_in[27] + L*512;
    const float* f2b = (const float*)d_in[29] + L*128;
    const float* l2w = (const float*)d_in[30] + L*128;
    const float* l2b = (const float*)d_in[31] + L*128;
    attn32<1024,1><<<dim3(512), 256, 0, stream>>>(qkvb, vT, obuf);
    if (L < 1) {
      mega_mlp<2,1><<<dim3(512), 256, 0, stream>>>(obuf, w_out_d + L*16384, ob, tok,
          l1w, l1b, w_ff1_d + L*65536, f1b, w_ff2_d + L*65536, f2b, l2w, l2b,
          w_qkv_d + 49152, (const float*)d_in[21] + 384, qkvb, vT, 10, QS);
    } else {
      mega_mlp<2,0><<<dim3(512), 256, 0, stream>>>(obuf, w_out_d + L*16384, ob, tok,
          l1w, l1b, w_ff1_d + L*65536, f1b, w_ff2_d + L*65536, f2b, l2w, l2b,
          w_qkv_d, (const float*)d_in[21], qkvb, vT, 10, QS);
    }
  }

  // recon + fused unpatchify (fp32 out)
  mfma_gemm<128,4,0,2><<<dim3(6,128), 256, 0, stream>>>(tok, w_rec, b_recon, out, 16384, 768, 128, nullptr, 0, 1.f);
}

// Round 6
// 330.886 us; speedup vs baseline: 1.2093x; 1.0310x over previous
//
#include <hip/hip_runtime.h>
#include <math.h>

// B=16, C=3, H=W=512, P=16, D=128, NH=4, hd=32, GH=GW=32, NP=1024, PD=768, NV=256, FF=512
typedef unsigned short ushort_t;
typedef __attribute__((ext_vector_type(8))) short bf16x8;
typedef __attribute__((ext_vector_type(4))) float f32x4;
typedef __attribute__((ext_vector_type(16))) float f32x16;
typedef __attribute__((ext_vector_type(2))) unsigned uint2v;

__device__ __forceinline__ ushort_t f2bf(float f){
  union{float f; unsigned u;} v; v.f = f;
  unsigned r = v.u + 0x7FFFu + ((v.u >> 16) & 1u);
  return (ushort_t)(r >> 16);
}
__device__ __forceinline__ float bf2f(ushort_t h){
  union{unsigned u; float f;} v; v.u = ((unsigned)h) << 16; return v.f;
}
__device__ __forceinline__ float gelu_exact(float v){
  return 0.5f * v * (1.f + erff(v * 0.70710678118654752f));
}
#define GLD16(gp, lp) __builtin_amdgcn_global_load_lds( \
    (const __attribute__((address_space(1))) void*)(gp), \
    (__attribute__((address_space(3))) void*)(lp), 16, 0, 0)

static __device__ __forceinline__ f32x4 mfma16(bf16x8 a, bf16x8 b, f32x4 c){
  return __builtin_amdgcn_mfma_f32_16x16x32_bf16(a, b, c, 0, 0, 0);
}
static __device__ __forceinline__ f32x16 mfma32(bf16x8 a, bf16x8 b, f32x16 c){
  return __builtin_amdgcn_mfma_f32_32x32x16_bf16(a, b, c, 0, 0, 0);
}

// ---------------------------------------------------------------------------
// bf16 MFMA GEMM (LDS-staged): patch embed, qkv0, recon.
// ---------------------------------------------------------------------------
template<int BT, int MI, int SRC, int EPI>
__global__ __launch_bounds__(256) void mfma_gemm(
    const ushort_t* __restrict__ A, const ushort_t* __restrict__ W,
    const float* __restrict__ bias, void* __restrict__ Cout,
    int M, int N, int K, ushort_t* __restrict__ vT, int slog, float qs)
{
  __shared__ ushort_t smem[BT*64 + BT*64];
  ushort_t* Al = smem;
  ushort_t* Wl = smem + BT*64;
  const int tid = threadIdx.x;
  const int lane = tid & 63, w = tid >> 6;
  const int wr = w >> 1, wc = w & 1;
  const int g = lane >> 4, lq = lane & 15;
  const int m0 = blockIdx.y * BT, n0 = blockIdx.x * BT;

  const f32x4 zf = {0.f, 0.f, 0.f, 0.f};
  f32x4 acc[MI][MI];
#pragma unroll
  for (int i = 0; i < MI; ++i)
#pragma unroll
    for (int j = 0; j < MI; ++j) acc[i][j] = zf;

  float bv[MI];
#pragma unroll
  for (int ni = 0; ni < MI; ++ni) bv[ni] = bias[n0 + wc*(BT/2) + ni*16 + lq];

  const int KT = K >> 6;
  for (int kt = 0; kt < KT; ++kt) {
    if (kt) __syncthreads();
    const int k0 = kt << 6;
#pragma unroll
    for (int i = 0; i < BT/32; ++i) {
      int chunk = i*256 + tid;
      int row = chunk >> 3, c = chunk & 7;
      int kk = k0 + ((c ^ (row & 7)) << 3);
      const ushort_t* src;
      if (SRC == 0) {
        src = A + (size_t)(m0 + row) * K + kk;
      } else {
        int gm = m0 + row;
        int bb = gm >> 10, pp = gm & 1023, gh = pp >> 5, gw = pp & 31;
        int ci = kk >> 8, rem = kk & 255, py = rem >> 4, px = rem & 15;
        src = A + ((size_t)((bb*3 + ci)*512 + gh*16 + py) * 512 + gw*16 + px);
      }
      GLD16(src, (char*)Al + chunk*16);
    }
#pragma unroll
    for (int i = 0; i < BT/32; ++i) {
      int chunk = i*256 + tid;
      int row = chunk >> 3, c = chunk & 7;
      int kk = k0 + ((c ^ (row & 7)) << 3);
      GLD16(W + (size_t)(n0 + row) * K + kk, (char*)Wl + chunk*16);
    }
    __syncthreads();
#pragma unroll
    for (int ks = 0; ks < 2; ++ks) {
      bf16x8 af[MI], bfr[MI];
#pragma unroll
      for (int mi = 0; mi < MI; ++mi) {
        int row = wr*(BT/2) + mi*16 + lq;
        int c = (ks*4 + g) ^ (row & 7);
        af[mi] = *(const bf16x8*)((const char*)Al + row*128 + c*16);
      }
#pragma unroll
      for (int ni = 0; ni < MI; ++ni) {
        int row = wc*(BT/2) + ni*16 + lq;
        int c = (ks*4 + g) ^ (row & 7);
        bfr[ni] = *(const bf16x8*)((const char*)Wl + row*128 + c*16);
      }
#pragma unroll
      for (int mi = 0; mi < MI; ++mi)
#pragma unroll
        for (int ni = 0; ni < MI; ++ni)
          acc[mi][ni] = mfma16(af[mi], bfr[ni], acc[mi][ni]);
    }
  }

  if (EPI == 3 && n0 >= 256) {
    const int Sm1 = (1 << slog) - 1;
#pragma unroll
    for (int mi = 0; mi < MI; ++mi) {
      int gm0 = m0 + wr*(BT/2) + mi*16 + g*4;
      int bb = gm0 >> slog, s0 = gm0 & Sm1;
#pragma unroll
      for (int ni = 0; ni < MI; ++ni) {
        int n = n0 + wc*(BT/2) + ni*16 + lq;
        int vcol = n - 256, hh = vcol >> 5, dd = vcol & 31;
        unsigned pw0 = ((unsigned)f2bf(acc[mi][ni][0] + bv[ni])) |
                       (((unsigned)f2bf(acc[mi][ni][1] + bv[ni])) << 16);
        unsigned pw1 = ((unsigned)f2bf(acc[mi][ni][2] + bv[ni])) |
                       (((unsigned)f2bf(acc[mi][ni][3] + bv[ni])) << 16);
        uint2 pk; pk.x = pw0; pk.y = pw1;
        *(uint2*)(vT + (((size_t)(bb*4 + hh)*32 + dd) << slog) + s0) = pk;
      }
    }
    return;
  }

  if (EPI == 2) {
    float* img = (float*)Cout;
#pragma unroll
    for (int mi = 0; mi < MI; ++mi) {
#pragma unroll
      for (int r = 0; r < 4; ++r) {
        int gm = m0 + wr*(BT/2) + mi*16 + g*4 + r;
        int bb = gm >> 10, pp = gm & 1023, gh = pp >> 5, gw = pp & 31;
#pragma unroll
        for (int ni = 0; ni < MI; ++ni) {
          int n = n0 + wc*(BT/2) + ni*16 + lq;
          int ci = n >> 8, rem = n & 255, py = rem >> 4, px = rem & 15;
          img[(size_t)((bb*3 + ci)*512 + gh*16 + py)*512 + gw*16 + px] =
              acc[mi][ni][r] + bv[ni];
        }
      }
    }
  } else {
    const float cs = (EPI == 3 && n0 < 128) ? qs : 1.0f;
    __syncthreads();
    constexpr int CPR = BT/8;
#pragma unroll
    for (int mi = 0; mi < MI; ++mi)
#pragma unroll
      for (int ni = 0; ni < MI; ++ni)
#pragma unroll
        for (int r = 0; r < 4; ++r) {
          int row = wr*(BT/2) + mi*16 + g*4 + r;
          int col = wc*(BT/2) + ni*16 + lq;
          float v = acc[mi][ni][r] + bv[ni];
          if (EPI == 3) v *= cs;
          int cc = (col >> 3) ^ (row & (CPR-1));
          smem[row*BT + cc*8 + (col & 7)] = f2bf(v);
        }
    __syncthreads();
    ushort_t* Co = (ushort_t*)Cout;
#pragma unroll
    for (int i = 0; i < BT*BT/2048; ++i) {
      int chunk = i*256 + tid;
      int row = chunk / CPR, cc = chunk % CPR;
      int c = cc ^ (row & (CPR-1));
      bf16x8 v = *(const bf16x8*)((const char*)smem + chunk*16);
      *(bf16x8*)(Co + (size_t)(m0+row)*N + n0 + c*8) = v;
    }
  }
}

// ---------------------------------------------------------------------------
// MEGA layer-tail, 8-wave version: out-proj + LN1 + FFN(GELU) + LN2 [+ qkv].
// 512 threads; wave w owns output cols w*16..w*16+15 of each 128-col pass.
// Per-wave MFMA chain is half the 4-wave version; 2 blocks/CU -> 16 waves/CU.
// ---------------------------------------------------------------------------
template<int MI2, int QKV>
__global__ __launch_bounds__(512, 4) void mega8(
    const ushort_t* __restrict__ Ao, const ushort_t* __restrict__ Wo,
    const float* __restrict__ bo, ushort_t* __restrict__ X,
    const float* __restrict__ l1w, const float* __restrict__ l1b,
    const ushort_t* __restrict__ W1, const float* __restrict__ b1,
    const ushort_t* __restrict__ W2, const float* __restrict__ b2,
    const float* __restrict__ l2w, const float* __restrict__ l2b,
    const ushort_t* __restrict__ Wq, const float* __restrict__ bq,
    ushort_t* __restrict__ qkvb, ushort_t* __restrict__ vT,
    int slog, float qs)
{
  constexpr int BM = MI2 * 16;
  constexpr int TB = BM * 128;              // bytes per 64-k LDS tile
  __shared__ __align__(16) ushort_t Xl[2*BM*64];
  __shared__ __align__(16) ushort_t Hl[8*BM*64];
  __shared__ __align__(16) float red[2][BM][8];
  const int tid = threadIdx.x, lane = tid & 63, w = tid >> 6;  // w in [0,8)
  const int g = lane >> 4, lq = lane & 15;
  const int m0 = blockIdx.x * BM;
  const int col0 = w*16 + lq;               // this lane's output column (of 128)
  const f32x4 zf = {0.f,0.f,0.f,0.f};

  // ---- P1: out-projection (K=128, N=128), direct-register ----
  f32x4 acc[MI2];
#pragma unroll
  for (int mi = 0; mi < MI2; ++mi) acc[mi] = zf;
  {
    bf16x8 a1[MI2][4], bo8[4];
#pragma unroll
    for (int mi = 0; mi < MI2; ++mi)
#pragma unroll
      for (int kf = 0; kf < 4; ++kf)
        a1[mi][kf] = *(const bf16x8*)(Ao + (size_t)(m0 + mi*16 + lq)*128 + kf*32 + g*8);
#pragma unroll
    for (int kf = 0; kf < 4; ++kf)
      bo8[kf] = *(const bf16x8*)(Wo + (size_t)col0*128 + kf*32 + g*8);
#pragma unroll
    for (int kf = 0; kf < 4; ++kf)
#pragma unroll
      for (int mi = 0; mi < MI2; ++mi)
        acc[mi] = mfma16(a1[mi][kf], bo8[kf], acc[mi]);
  }

  // ---- LN1: bias + residual, row stats, normalize; keep X' in regs ----
  float xp[MI2][4];
  {
    const float bv = bo[col0], lwv = l1w[col0], lbv = l1b[col0];
#pragma unroll
    for (int mi = 0; mi < MI2; ++mi)
#pragma unroll
      for (int r = 0; r < 4; ++r) {
        int row = m0 + mi*16 + g*4 + r;
        float v = acc[mi][r] + bv + bf2f(X[(size_t)row*128 + col0]);
        xp[mi][r] = v;
        float s = v, q = v*v;
        s += __shfl_xor(s,1); s += __shfl_xor(s,2); s += __shfl_xor(s,4); s += __shfl_xor(s,8);
        q += __shfl_xor(q,1); q += __shfl_xor(q,2); q += __shfl_xor(q,4); q += __shfl_xor(q,8);
        if (lq == 0) { red[0][mi*16+g*4+r][w] = s; red[1][mi*16+g*4+r][w] = q; }
      }
    __syncthreads();
#pragma unroll
    for (int mi = 0; mi < MI2; ++mi)
#pragma unroll
      for (int r = 0; r < 4; ++r) {
        int rl = mi*16 + g*4 + r;
        float4 s0 = *(const float4*)&red[0][rl][0], s1 = *(const float4*)&red[0][rl][4];
        float4 q0 = *(const float4*)&red[1][rl][0], q1 = *(const float4*)&red[1][rl][4];
        float s = s0.x+s0.y+s0.z+s0.w + s1.x+s1.y+s1.z+s1.w;
        float q = q0.x+q0.y+q0.z+q0.w + q1.x+q1.y+q1.z+q1.w;
        float mean = s * 0.0078125f;
        float var = q * 0.0078125f - mean*mean;
        float rstd = rsqrtf(var + 1e-5f);
        float val = (xp[mi][r]-mean)*rstd*lwv + lbv;
        xp[mi][r] = val;
        ushort_t hv = f2bf(val);
        X[(size_t)(m0+rl)*128 + col0] = hv;
        int kt = col0 >> 6, c8 = (col0 & 63) >> 3, he = col0 & 7;
        *(ushort_t*)((char*)Xl + kt*TB + rl*128 + ((c8 ^ (rl & 7)) << 4) + he*2) = hv;
      }
  }
  __syncthreads();

  // A fragments of X' (used by P2)
  bf16x8 a2[MI2][4];
#pragma unroll
  for (int mi = 0; mi < MI2; ++mi)
#pragma unroll
    for (int kf = 0; kf < 4; ++kf) {
      int kt = kf >> 1, row = mi*16 + lq;
      int c = ((kf & 1)*4 + g) ^ (row & 7);
      a2[mi][kf] = *(const bf16x8*)((const char*)Xl + kt*TB + row*128 + c*16);
    }

  // ---- P2: ff1 + GELU -> Hl (4 passes of 128 hidden cols) ----
#pragma unroll
  for (int hp = 0; hp < 4; ++hp) {
    const int hid = hp*128 + col0;
    bf16x8 b18[4];
#pragma unroll
    for (int kf = 0; kf < 4; ++kf)
      b18[kf] = *(const bf16x8*)(W1 + (size_t)hid*128 + kf*32 + g*8);
    f32x4 acc1[MI2];
#pragma unroll
    for (int mi = 0; mi < MI2; ++mi) acc1[mi] = zf;
#pragma unroll
    for (int kf = 0; kf < 4; ++kf)
#pragma unroll
      for (int mi = 0; mi < MI2; ++mi)
        acc1[mi] = mfma16(a2[mi][kf], b18[kf], acc1[mi]);
    const float bb = b1[hid];
    const int hkt = hid >> 6, hc8 = (hid & 63) >> 3, he = hid & 7;
#pragma unroll
    for (int mi = 0; mi < MI2; ++mi)
#pragma unroll
      for (int r = 0; r < 4; ++r) {
        int mrow = mi*16 + g*4 + r;
        float hv = gelu_exact(acc1[mi][r] + bb);
        *(ushort_t*)((char*)Hl + hkt*TB + mrow*128 + ((hc8 ^ (mrow & 7)) << 4) + he*2) = f2bf(hv);
      }
  }
  __syncthreads();

  // ---- P3: ff2 (K=512, A from Hl, W2 direct) ----
  f32x4 acc2[MI2];
#pragma unroll
  for (int mi = 0; mi < MI2; ++mi) acc2[mi] = zf;
#pragma unroll
  for (int kf = 0; kf < 16; ++kf) {
    int kt = kf >> 1;
    bf16x8 af[MI2], bfr;
#pragma unroll
    for (int mi = 0; mi < MI2; ++mi) {
      int row = mi*16 + lq;
      int c = ((kf & 1)*4 + g) ^ (row & 7);
      af[mi] = *(const bf16x8*)((const char*)Hl + kt*TB + row*128 + c*16);
    }
    bfr = *(const bf16x8*)(W2 + (size_t)col0*512 + kf*32 + g*8);
#pragma unroll
    for (int mi = 0; mi < MI2; ++mi)
      acc2[mi] = mfma16(af[mi], bfr, acc2[mi]);
  }

  // ---- LN2 (residual = xp regs) ----
  {
    const float bv = b2[col0], lwv = l2w[col0], lbv = l2b[col0];
#pragma unroll
    for (int mi = 0; mi < MI2; ++mi)
#pragma unroll
      for (int r = 0; r < 4; ++r) {
        float v = acc2[mi][r] + bv + xp[mi][r];
        xp[mi][r] = v;
        float s = v, q = v*v;
        s += __shfl_xor(s,1); s += __shfl_xor(s,2); s += __shfl_xor(s,4); s += __shfl_xor(s,8);
        q += __shfl_xor(q,1); q += __shfl_xor(q,2); q += __shfl_xor(q,4); q += __shfl_xor(q,8);
        if (lq == 0) { red[0][mi*16+g*4+r][w] = s; red[1][mi*16+g*4+r][w] = q; }
      }
    __syncthreads();
#pragma unroll
    for (int mi = 0; mi < MI2; ++mi)
#pragma unroll
      for (int r = 0; r < 4; ++r) {
        int rl = mi*16 + g*4 + r;
        float4 s0 = *(const float4*)&red[0][rl][0], s1 = *(const float4*)&red[0][rl][4];
        float4 q0 = *(const float4*)&red[1][rl][0], q1 = *(const float4*)&red[1][rl][4];
        float s = s0.x+s0.y+s0.z+s0.w + s1.x+s1.y+s1.z+s1.w;
        float q = q0.x+q0.y+q0.z+q0.w + q1.x+q1.y+q1.z+q1.w;
        float mean = s * 0.0078125f;
        float var = q * 0.0078125f - mean*mean;
        float rstd = rsqrtf(var + 1e-5f);
        float val = (xp[mi][r]-mean)*rstd*lwv + lbv;
        ushort_t hv = f2bf(val);
        X[(size_t)(m0+rl)*128 + col0] = hv;
        if (QKV) {
          int kt = col0 >> 6, c8 = (col0 & 63) >> 3, he = col0 & 7;
          *(ushort_t*)((char*)Xl + kt*TB + rl*128 + ((c8 ^ (rl & 7)) << 4) + he*2) = hv;
        }
      }
  }

  // ---- P4: next layer's qkv (3 passes of 128 cols) ----
  if (QKV) {
    __syncthreads();
    bf16x8 a3[MI2][4];
#pragma unroll
    for (int mi = 0; mi < MI2; ++mi)
#pragma unroll
      for (int kf = 0; kf < 4; ++kf) {
        int kt = kf >> 1, row = mi*16 + lq;
        int c = ((kf & 1)*4 + g) ^ (row & 7);
        a3[mi][kf] = *(const bf16x8*)((const char*)Xl + kt*TB + row*128 + c*16);
      }
    const int Sm1 = (1 << slog) - 1;
#pragma unroll
    for (int pp = 0; pp < 3; ++pp) {
      const int colq = pp*128 + col0;
      bf16x8 bq8[4];
#pragma unroll
      for (int kf = 0; kf < 4; ++kf)
        bq8[kf] = *(const bf16x8*)(Wq + (size_t)colq*128 + kf*32 + g*8);
      f32x4 aq[MI2];
#pragma unroll
      for (int mi = 0; mi < MI2; ++mi) aq[mi] = zf;
#pragma unroll
      for (int kf = 0; kf < 4; ++kf)
#pragma unroll
        for (int mi = 0; mi < MI2; ++mi)
          aq[mi] = mfma16(a3[mi][kf], bq8[kf], aq[mi]);
      const float bias = bq[colq];
      if (pp < 2) {
        const float sc = (pp == 0) ? qs : 1.f;
#pragma unroll
        for (int mi = 0; mi < MI2; ++mi)
#pragma unroll
          for (int r = 0; r < 4; ++r) {
            int row = m0 + mi*16 + g*4 + r;
            qkvb[(size_t)row*384 + colq] = f2bf((aq[mi][r] + bias)*sc);
          }
      } else {
        const int hh = col0 >> 5, dd = col0 & 31;
#pragma unroll
        for (int mi = 0; mi < MI2; ++mi) {
          int gm0 = m0 + mi*16 + g*4;
          int bb = gm0 >> slog, s0 = gm0 & Sm1;
          unsigned pw0 = ((unsigned)f2bf(aq[mi][0] + bias)) |
                         (((unsigned)f2bf(aq[mi][1] + bias)) << 16);
          unsigned pw1 = ((unsigned)f2bf(aq[mi][2] + bias)) |
                         (((unsigned)f2bf(aq[mi][3] + bias)) << 16);
          uint2 pk; pk.x = pw0; pk.y = pw1;
          *(uint2*)(vT + (((size_t)(bb*4 + hh)*32 + dd) << slog) + s0) = pk;
        }
      }
    }
  }
}

// ---------------------------------------------------------------------------
// 32x32 MFMA flash attention (unchanged)
// ---------------------------------------------------------------------------
template<int S, int JS>
__global__ __launch_bounds__(256) void attn32(
    const ushort_t* __restrict__ qkv, const ushort_t* __restrict__ vTg,
    ushort_t* __restrict__ o)
{
  constexpr int LDSB = (JS == 1) ? 16384 : 32768;
  __shared__ __align__(16) char smem[LDSB];
  const int tid = threadIdx.x, lane = tid & 63, w = tid >> 6;
  const int hi = lane >> 5, lq = lane & 31;
  int lin = blockIdx.x;
  int nid = (lin & 7) * 64 + (lin >> 3);
  int bx = nid & 7, bh = nid >> 3;
  int h = bh & 3, b = bh >> 2;
  const int q0 = (JS == 1) ? (bx*128 + w*32) : (bx*32);

  bf16x8 bq0 = *(const bf16x8*)(qkv + (size_t)(b*S + q0 + lq)*384 + h*32 + hi*8);
  bf16x8 bq1 = *(const bf16x8*)(qkv + (size_t)(b*S + q0 + lq)*384 + h*32 + 16 + hi*8);

  f32x16 O;
#pragma unroll
  for (int i = 0; i < 16; ++i) O[i] = 0.f;
  const f32x16 z16 = O;
  float l = 0.f;

  auto stageK = [&](char* Kb, int j0, int ci){
    int k = ci >> 2, cp = ci & 3, c = cp ^ (k & 3);
    GLD16(qkv + (size_t)(b*S + j0 + k)*384 + 128 + h*32 + c*8, Kb + ci*16);
  };
  auto stageV = [&](char* Vb, int j0, int ci){
    int d = ci >> 3, cp = ci & 7, c = cp ^ (d & 7);
    GLD16(vTg + (size_t)(bh*32 + d)*S + j0 + c*8, Vb + ci*16);
  };

  auto sm_pack = [&](const f32x16& stv, unsigned* wd){
    float p[16];
#pragma unroll
    for (int r = 0; r < 16; ++r) { p[r] = __expf(stv[r]); l += p[r]; }
#pragma unroll
    for (int i = 0; i < 8; ++i) {
      unsigned u0 = __float_as_uint(p[2*i])   + 0x8000u;
      unsigned u1 = __float_as_uint(p[2*i+1]) + 0x8000u;
      wd[i] = (u0 >> 16) | (u1 & 0xFFFF0000u);
    }
  };
  auto pvstep = [&](unsigned* wd, const char* Vb, int mt){
    uint2v s02 = __builtin_amdgcn_permlane32_swap(wd[0], wd[2], false, false);
    uint2v s13 = __builtin_amdgcn_permlane32_swap(wd[1], wd[3], false, false);
    uint2v s46 = __builtin_amdgcn_permlane32_swap(wd[4], wd[6], false, false);
    uint2v s57 = __builtin_amdgcn_permlane32_swap(wd[5], wd[7], false, false);
    union { unsigned u[4]; bf16x8 v; } pa0, pa1;
    pa0.u[0] = s02[0]; pa0.u[1] = s13[0]; pa0.u[2] = s02[1]; pa0.u[3] = s13[1];
    pa1.u[0] = s46[0]; pa1.u[1] = s57[0]; pa1.u[2] = s46[1]; pa1.u[3] = s57[1];
    int d = lq;
    bf16x8 v0 = *(const bf16x8*)(Vb + d*128 + (((mt*4 + hi)     ^ (d & 7)) << 4));
    bf16x8 v1 = *(const bf16x8*)(Vb + d*128 + (((mt*4 + 2 + hi) ^ (d & 7)) << 4));
    O = mfma32(pa0.v, v0, O);
    O = mfma32(pa1.v, v1, O);
  };
  auto computeTile = [&](const char* Kb, const char* Vb){
    const int k0 = lq, k1 = 32 + lq;
    bf16x8 a00 = *(const bf16x8*)(Kb + k0*64 + (((hi)     ^ (k0 & 3)) << 4));
    bf16x8 a01 = *(const bf16x8*)(Kb + k0*64 + (((2 + hi) ^ (k0 & 3)) << 4));
    f32x16 st0 = mfma32(a00, bq0, z16);
    st0 = mfma32(a01, bq1, st0);
    bf16x8 a10 = *(const bf16x8*)(Kb + k1*64 + (((hi)     ^ (k1 & 3)) << 4));
    bf16x8 a11 = *(const bf16x8*)(Kb + k1*64 + (((2 + hi) ^ (k1 & 3)) << 4));
    f32x16 st1 = mfma32(a10, bq0, z16);
    st1 = mfma32(a11, bq1, st1);
    unsigned wd0[8], wd1[8];
    sm_pack(st0, wd0);
    sm_pack(st1, wd1);
    pvstep(wd0, Vb, 0);
    pvstep(wd1, Vb, 1);
  };

  if (JS == 4) {
    char* Kb = smem + w*8192;
    char* Vb = Kb + 4096;
    const int j0 = w*64;
#pragma unroll
    for (int i = 0; i < 4; ++i) stageK(Kb, j0, i*64 + lane);
#pragma unroll
    for (int i = 0; i < 4; ++i) stageV(Vb, j0, i*64 + lane);
    __syncthreads();
    computeTile(Kb, Vb);
    float lw = l + __shfl_xor(l, 32);
    __syncthreads();
    float* F = (float*)smem;
#pragma unroll
    for (int r = 0; r < 16; ++r) F[(w*16 + r)*64 + lane] = O[r];
    if (hi == 0) F[4096 + w*32 + lq] = lw;
    __syncthreads();
    if (w == 0) {
      float lt = F[4096 + lq] + F[4096 + 32 + lq] + F[4096 + 64 + lq] + F[4096 + 96 + lq];
      float linv = 1.f / lt;
#pragma unroll
      for (int r = 0; r < 16; ++r) {
        float s = F[r*64 + lane] + F[(16 + r)*64 + lane] +
                  F[(32 + r)*64 + lane] + F[(48 + r)*64 + lane];
        int qr = (r & 3) + 8*(r >> 2) + 4*hi;
        float li = __shfl(linv, qr);
        o[(size_t)(b*S + q0 + qr)*128 + h*32 + lq] = f2bf(s*li);
      }
    }
  } else {
    char* K0 = smem, *V0 = smem + 4096, *K1 = smem + 8192, *V1 = smem + 12288;
    stageK(K0, 0, tid);
    stageV(V0, 0, tid);
    const int NT = S/64;
    for (int t = 0; t < NT; ++t) {
      __syncthreads();
      if (t + 1 < NT) {
        char* Kb = (t & 1) ? K0 : K1;
        char* Vb = (t & 1) ? V0 : V1;
        stageK(Kb, (t + 1)*64, tid);
        stageV(Vb, (t + 1)*64, tid);
      }
      computeTile((t & 1) ? K1 : K0, (t & 1) ? V1 : V0);
    }
    float ltot = l + __shfl_xor(l, 32);
    float linv = 1.f / ltot;
#pragma unroll
    for (int r = 0; r < 16; ++r) {
      int qr = (r & 3) + 8*(r >> 2) + 4*hi;
      float li = __shfl(linv, qr);
      o[(size_t)(b*S + q0 + qr)*128 + h*32 + lq] = f2bf(O[r]*li);
    }
  }
}

// ---------------------------------------------------------------------------
// fp32 -> bf16 cast (image + all weights)
// ---------------------------------------------------------------------------
struct CastArgs {
  const float* src[11];
  ushort_t* dst[11];
  int start[11];
};
__global__ __launch_bounds__(256) void cast_all(CastArgs a, int total8){
  int i = blockIdx.x*256 + threadIdx.x;
  if (i >= total8) return;
  int s = 0;
#pragma unroll
  for (int k = 1; k < 11; ++k) if (i >= a.start[k]) s = k;
  int off = (i - a.start[s]) * 8;
  const float* sp = a.src[s] + off;
  float4 f0 = *(const float4*)sp;
  float4 f1 = *(const float4*)(sp + 4);
  bf16x8 r;
  r[0]=(short)f2bf(f0.x); r[1]=(short)f2bf(f0.y); r[2]=(short)f2bf(f0.z); r[3]=(short)f2bf(f0.w);
  r[4]=(short)f2bf(f1.x); r[5]=(short)f2bf(f1.y); r[6]=(short)f2bf(f1.z); r[7]=(short)f2bf(f1.w);
  *(bf16x8*)(a.dst[s] + off) = r;
}

// ---------------------------------------------------------------------------
// gather / fill / scatter (bf16 tokens)
// ---------------------------------------------------------------------------
__global__ __launch_bounds__(256) void gather_k(const ushort_t* __restrict__ tok,
    const int* __restrict__ vis, ushort_t* __restrict__ xe){
  int i = blockIdx.x*256 + threadIdx.x;
  int r = i >> 4, e = (i & 15)*8;
  int b = r >> 8;
  int p = vis[r];
  *(bf16x8*)(xe + (size_t)r*128 + e) = *(const bf16x8*)(tok + ((size_t)b*1024 + p)*128 + e);
}

__global__ __launch_bounds__(256) void fill_k(const float* __restrict__ mask_tok,
    const float* __restrict__ pos, ushort_t* __restrict__ full){
  int i = blockIdx.x*256 + threadIdx.x;
  int off0 = i*8;
  int d = off0 & 127;
  int p = (off0 >> 7) & 1023;
  float4 m0 = *(const float4*)(mask_tok + d);
  float4 m1 = *(const float4*)(mask_tok + d + 4);
  const float* pp = pos + (size_t)p*128 + d;
  float4 p0 = *(const float4*)pp, p1 = *(const float4*)(pp + 4);
  bf16x8 r;
  r[0]=(short)f2bf(m0.x+p0.x); r[1]=(short)f2bf(m0.y+p0.y);
  r[2]=(short)f2bf(m0.z+p0.z); r[3]=(short)f2bf(m0.w+p0.w);
  r[4]=(short)f2bf(m1.x+p1.x); r[5]=(short)f2bf(m1.y+p1.y);
  r[6]=(short)f2bf(m1.z+p1.z); r[7]=(short)f2bf(m1.w+p1.w);
  *(bf16x8*)(full + off0) = r;
}

__global__ __launch_bounds__(256) void scatter_k(const ushort_t* __restrict__ enc,
    const int* __restrict__ vis, const float* __restrict__ pos, ushort_t* __restrict__ full){
  int i = blockIdx.x*256 + threadIdx.x;
  int r = i >> 4, e = (i & 15)*8;
  int b = r >> 8;
  int p = vis[r];
  bf16x8 ev = *(const bf16x8*)(enc + (size_t)r*128 + e);
  const float* pp = pos + (size_t)p*128 + e;
  float4 p0 = *(const float4*)pp, p1 = *(const float4*)(pp + 4);
  bf16x8 out;
  out[0]=(short)f2bf(bf2f((ushort_t)ev[0]) + p0.x);
  out[1]=(short)f2bf(bf2f((ushort_t)ev[1]) + p0.y);
  out[2]=(short)f2bf(bf2f((ushort_t)ev[2]) + p0.z);
  out[3]=(short)f2bf(bf2f((ushort_t)ev[3]) + p0.w);
  out[4]=(short)f2bf(bf2f((ushort_t)ev[4]) + p1.x);
  out[5]=(short)f2bf(bf2f((ushort_t)ev[5]) + p1.y);
  out[6]=(short)f2bf(bf2f((ushort_t)ev[6]) + p1.z);
  out[7]=(short)f2bf(bf2f((ushort_t)ev[7]) + p1.w);
  *(bf16x8*)(full + ((size_t)b*1024 + p)*128 + e) = out;
}

// ---------------------------------------------------------------------------
// Host orchestration
// ---------------------------------------------------------------------------
extern "C" void kernel_launch(void* const* d_in, const int* in_sizes, int n_in,
                              void* d_out, int out_size, void* d_ws, size_t ws_size,
                              hipStream_t stream)
{
  const float* x        = (const float*)d_in[0];
  const int*   vis      = (const int*)d_in[1];
  const float* b_patch  = (const float*)d_in[3];
  const float* mask_tok = (const float*)d_in[4];
  const float* pos      = (const float*)d_in[5];
  const float* b_recon  = (const float*)d_in[7];
  float* out = (float*)d_out;
  const float QS = 0.17677669529663687f;   // 1/sqrt(32), folded into q

  ushort_t* ws    = (ushort_t*)d_ws;
  ushort_t* tok   = ws;                     // 16384x128
  ushort_t* xe    = tok  + 2097152;         // 4096x128
  ushort_t* qkvb  = xe   + 524288;          // 16384x512
  ushort_t* obuf  = qkvb + 8388608;         // 16384x128
  ushort_t* tbuf  = obuf + 2097152;         // (unused)
  ushort_t* xbf   = tbuf + 2097152;         // bf16 image
  ushort_t* wbf   = xbf  + 12582912;        // bf16 weights

  ushort_t* w_qkv_e = wbf;
  ushort_t* w_out_e = w_qkv_e + 294912;
  ushort_t* w_ff1_e = w_out_e + 98304;
  ushort_t* w_ff2_e = w_ff1_e + 393216;
  ushort_t* w_qkv_d = w_ff2_e + 393216;
  ushort_t* w_out_d = w_qkv_d + 98304;
  ushort_t* w_ff1_d = w_out_d + 32768;
  ushort_t* w_ff2_d = w_ff1_d + 131072;
  ushort_t* w_pat   = w_ff2_d + 131072;
  ushort_t* w_rec   = w_pat   + 98304;
  ushort_t* vT      = w_rec   + 98304;      // [16][4][32][S<=1024]

  CastArgs ca;
  const float* srcs[11] = {x, (const float*)d_in[8], (const float*)d_in[10],
                           (const float*)d_in[14], (const float*)d_in[16],
                           (const float*)d_in[20], (const float*)d_in[22],
                           (const float*)d_in[26], (const float*)d_in[28],
                           (const float*)d_in[2], (const float*)d_in[6]};
  ushort_t* dsts[11] = {xbf, w_qkv_e, w_out_e, w_ff1_e, w_ff2_e,
                        w_qkv_d, w_out_d, w_ff1_d, w_ff2_d, w_pat, w_rec};
  int sizes[11] = {12582912, 294912, 98304, 393216, 393216,
                   98304, 32768, 131072, 131072, 98304, 98304};
  int acc8 = 0;
  for (int k = 0; k < 11; ++k){ ca.src[k]=srcs[k]; ca.dst[k]=dsts[k]; ca.start[k]=acc8; acc8 += sizes[k]/8; }
  cast_all<<<dim3((acc8 + 255)/256), 256, 0, stream>>>(ca, acc8);

  // patch embed (fused Unfold gather) -> tok [16384,128]
  mfma_gemm<64,2,1,0><<<dim3(2,256), 256, 0, stream>>>(xbf, w_pat, b_patch, tok, 16384, 128, 768, nullptr, 0, 1.f);
  gather_k<<<dim3(256), 256, 0, stream>>>(tok, vis, xe);

  // encoder: qkv for layer 0, then per layer {attn, mega8(+qkv_next)}
  mfma_gemm<64,2,0,3><<<dim3(6,64), 256, 0, stream>>>(xe, w_qkv_e, (const float*)d_in[9], qkvb, 4096, 384, 128, vT, 8, QS);
  for (int L = 0; L < 6; ++L) {
    const float* ob  = (const float*)d_in[11] + L*128;
    const float* l1w = (const float*)d_in[12] + L*128;
    const float* l1b = (const float*)d_in[13] + L*128;
    const float* f1b = (const float*)d_in[15] + L*512;
    const float* f2b = (const float*)d_in[17] + L*128;
    const float* l2w = (const float*)d_in[18] + L*128;
    const float* l2b = (const float*)d_in[19] + L*128;
    attn32<256,4><<<dim3(512), 256, 0, stream>>>(qkvb, vT, obuf);
    if (L < 5) {
      mega8<1,1><<<dim3(256), 512, 0, stream>>>(obuf, w_out_e + L*16384, ob, xe,
          l1w, l1b, w_ff1_e + L*65536, f1b, w_ff2_e + L*65536, f2b, l2w, l2b,
          w_qkv_e + (L+1)*49152, (const float*)d_in[9] + (L+1)*384, qkvb, vT, 8, QS);
    } else {
      mega8<1,0><<<dim3(256), 512, 0, stream>>>(obuf, w_out_e + L*16384, ob, xe,
          l1w, l1b, w_ff1_e + L*65536, f1b, w_ff2_e + L*65536, f2b, l2w, l2b,
          w_qkv_e, (const float*)d_in[9], qkvb, vT, 8, QS);
    }
  }

  fill_k<<<dim3(1024), 256, 0, stream>>>(mask_tok, pos, tok);
  scatter_k<<<dim3(256), 256, 0, stream>>>(xe, vis, pos, tok);

  // decoder: qkv for layer 0, then per layer {attn, mega8(+qkv_next)}
  mfma_gemm<128,4,0,3><<<dim3(3,128), 256, 0, stream>>>(tok, w_qkv_d, (const float*)d_in[21], qkvb, 16384, 384, 128, vT, 10, QS);
  for (int L = 0; L < 2; ++L) {
    const float* ob  = (const float*)d_in[23] + L*128;
    const float* l1w = (const float*)d_in[24] + L*128;
    const float* l1b = (const float*)d_in[25] + L*128;
    const float* f1b = (const float*)d_in[27] + L*512;
    const float* f2b = (const float*)d_in[29] + L*128;
    const float* l2w = (const float*)d_in[30] + L*128;
    const float* l2b = (const float*)d_in[31] + L*128;
    attn32<1024,1><<<dim3(512), 256, 0, stream>>>(qkvb, vT, obuf);
    if (L < 1) {
      mega8<2,1><<<dim3(512), 512, 0, stream>>>(obuf, w_out_d + L*16384, ob, tok,
          l1w, l1b, w_ff1_d + L*65536, f1b, w_ff2_d + L*65536, f2b, l2w, l2b,
          w_qkv_d + 49152, (const float*)d_in[21] + 384, qkvb, vT, 10, QS);
    } else {
      mega8<2,0><<<dim3(512), 512, 0, stream>>>(obuf, w_out_d + L*16384, ob, tok,
          l1w, l1b, w_ff1_d + L*65536, f1b, w_ff2_d + L*65536, f2b, l2w, l2b,
          w_qkv_d, (const float*)d_in[21], qkvb, vT, 10, QS);
    }
  }

  // recon + fused unpatchify (fp32 out)
  mfma_gemm<128,4,0,2><<<dim3(6,128), 256, 0, stream>>>(tok, w_rec, b_recon, out, 16384, 768, 128, nullptr, 0, 1.f);
}